// Round 1
// baseline (397.328 us; speedup 1.0000x reference)
//
#include <hip/hip_runtime.h>
#include <hip/hip_bf16.h>

// RecognitionLattice: RNN-T style lattice loss.
// Pipeline: transpose/cast weights -> cemb gather -> fproj GEMM (bf16 MFMA)
//        -> joint GEMM h=tanh(fproj+cemb), logits=h@Wo, fused logsumexp
//        -> per-batch forward DP (1 wave each).

#define BB 4
#define TT 512
#define UU 96
#define FF 512
#define HH 512
#define VV 256
#define NV (VV + 1)    // 257 vocab incl. blank
#define NU (UU + 1)    // 97 lattice rows per t
#define NPAD 272       // 17 * 16, padded N for MFMA
#define NEG_INF (-1e30f)

typedef __bf16 bf16;
typedef __bf16 bf16x8 __attribute__((ext_vector_type(8)));
typedef float f32x4 __attribute__((ext_vector_type(4)));

__device__ __forceinline__ float fast_tanh(float x) {
    float e = __expf(2.0f * x);
    return 1.0f - 2.0f / (e + 1.0f);
}

__device__ __forceinline__ float lae(float x, float y) {
    float m = fmaxf(x, y);
    float d = fminf(x, y) - m;
    return m + __logf(1.0f + __expf(d));
}

// ---- prep: Wf^T cast to bf16: Wf_t[n][k] = Wf[k][n] ----
__global__ void k_wf_t(const float* __restrict__ Wf, bf16* __restrict__ Wf_t) {
    int n = blockIdx.x;
    for (int k = threadIdx.x; k < FF; k += blockDim.x)
        Wf_t[n * FF + k] = (bf16)Wf[k * HH + n];
}

// ---- prep: Wo^T cast to bf16 with zero pad rows: Wo_t[n][k] = Wo[k][n] ----
__global__ void k_wo_t(const float* __restrict__ Wo, bf16* __restrict__ Wo_t) {
    int n = blockIdx.x;  // 0..271
    for (int k = threadIdx.x; k < HH; k += blockDim.x) {
        float v = (n < NV) ? Wo[k * NV + n] : 0.0f;
        Wo_t[n * HH + k] = (bf16)v;
    }
}

// ---- prep: cemb[b][u][:] = E[ctx(b,u)][:] ----
__global__ void k_cemb(const float* __restrict__ E, const int* __restrict__ labels,
                       float* __restrict__ cemb) {
    int u = blockIdx.x;  // 0..96
    int b = blockIdx.y;
    int ctx = (u == 0) ? 0 : labels[b * UU + (u - 1)];
    const float4* src = (const float4*)&E[(size_t)ctx * HH];
    float4* dst = (float4*)&cemb[((size_t)b * NU + u) * HH];
    for (int i = threadIdx.x; i < HH / 4; i += blockDim.x) dst[i] = src[i];
}

// ---- fproj = frames @ Wf  (bf16 MFMA, fp32 out) ----
// grid (2048/64, 512/64), block 256. 64x64 tile, wave = 16 rows x 64 cols.
__global__ __launch_bounds__(256, 2) void k_fproj(
    const float* __restrict__ frames, const bf16* __restrict__ Wf_t,
    float* __restrict__ fproj) {
    __shared__ bf16 Alds[64 * 40];
    __shared__ bf16 Blds[64 * 40];
    const int tid = threadIdx.x;
    const int r0 = blockIdx.x * 64;
    const int n0 = blockIdx.y * 64;
    const int lane = tid & 63, w = tid >> 6;
    const int c = lane & 15, g = lane >> 4;

    const int srow = tid >> 2, sko = (tid & 3) * 8;
    const float* fptr = frames + (size_t)(r0 + srow) * FF + sko;
    const bf16* wptr = Wf_t + (size_t)(n0 + srow) * FF + sko;

    f32x4 acc[4];
#pragma unroll
    for (int j = 0; j < 4; ++j) acc[j] = (f32x4){0.f, 0.f, 0.f, 0.f};

    for (int kt = 0; kt < FF; kt += 32) {
        float4 f1 = *(const float4*)(fptr + kt);
        float4 f2 = *(const float4*)(fptr + kt + 4);
        bf16x8 av = {(bf16)f1.x, (bf16)f1.y, (bf16)f1.z, (bf16)f1.w,
                     (bf16)f2.x, (bf16)f2.y, (bf16)f2.z, (bf16)f2.w};
        *(bf16x8*)&Alds[srow * 40 + sko] = av;
        *(bf16x8*)&Blds[srow * 40 + sko] = *(const bf16x8*)(wptr + kt);
        __syncthreads();
        const int m = w * 16;
        bf16x8 af = *(const bf16x8*)&Alds[(m + c) * 40 + g * 8];
#pragma unroll
        for (int j = 0; j < 4; ++j) {
            bf16x8 bv = *(const bf16x8*)&Blds[(j * 16 + c) * 40 + g * 8];
            acc[j] = __builtin_amdgcn_mfma_f32_16x16x32_bf16(af, bv, acc[j], 0, 0, 0);
        }
        __syncthreads();
    }
    const int m = w * 16;
#pragma unroll
    for (int j = 0; j < 4; ++j)
#pragma unroll
        for (int r = 0; r < 4; ++r)
            fproj[(size_t)(r0 + m + g * 4 + r) * HH + n0 + j * 16 + c] = acc[j][r];
}

// ---- joint: logits = tanh(fproj[t]+cemb[u]) @ Wo, fused log_softmax extract ----
// grid (49664/128, B), block 256. 128-row x 272-col tile; wave = 2 Mtiles x 17 Ntiles.
__global__ __launch_bounds__(256, 2) void k_joint(
    const float* __restrict__ fproj, const float* __restrict__ cemb,
    const bf16* __restrict__ Wo_t, const int* __restrict__ labels,
    const int* __restrict__ num_frames,
    float* __restrict__ blank_arr, float* __restrict__ lex_arr) {
    __shared__ bf16 Alds[128 * 40];   // 10240 B
    __shared__ bf16 Blds[NPAD * 40];  // 21760 B
    const int tid = threadIdx.x;
    const int b = blockIdx.y;
    const int r0 = blockIdx.x * 128;
    const int nf = num_frames[b];
    if (r0 / NU >= nf) return;  // whole tile beyond active frames: outputs unused

    const int lane = tid & 63, w = tid >> 6;
    const int c = lane & 15, g = lane >> 4;

    // A-staging: 128 rows x 32 k per iter = 512 vec8 tasks; 2 per thread
    const float* pfA[2];
    const float* pcA[2];
    int arow[2], ako[2];
#pragma unroll
    for (int i = 0; i < 2; ++i) {
        int idx = tid + i * 256;
        int row = idx >> 2, ko = (idx & 3) * 8;
        int gr = r0 + row;
        int t = gr / NU, u = gr - t * NU;
        arow[i] = row;
        ako[i] = ko;
        pfA[i] = fproj + ((size_t)(b * TT + t)) * HH + ko;
        pcA[i] = cemb + ((size_t)(b * NU + u)) * HH + ko;
    }

    f32x4 acc[2][17];
#pragma unroll
    for (int mt = 0; mt < 2; ++mt)
#pragma unroll
        for (int j = 0; j < 17; ++j) acc[mt][j] = (f32x4){0.f, 0.f, 0.f, 0.f};

    for (int kt = 0; kt < HH; kt += 32) {
#pragma unroll
        for (int i = 0; i < 2; ++i) {
            float4 f1 = *(const float4*)(pfA[i] + kt);
            float4 f2 = *(const float4*)(pfA[i] + kt + 4);
            float4 c1 = *(const float4*)(pcA[i] + kt);
            float4 c2 = *(const float4*)(pcA[i] + kt + 4);
            bf16x8 av = {(bf16)fast_tanh(f1.x + c1.x), (bf16)fast_tanh(f1.y + c1.y),
                         (bf16)fast_tanh(f1.z + c1.z), (bf16)fast_tanh(f1.w + c1.w),
                         (bf16)fast_tanh(f2.x + c2.x), (bf16)fast_tanh(f2.y + c2.y),
                         (bf16)fast_tanh(f2.z + c2.z), (bf16)fast_tanh(f2.w + c2.w)};
            *(bf16x8*)&Alds[arow[i] * 40 + ako[i]] = av;
        }
        // B-staging: 272 rows x 32 k = 1088 vec8 tasks
#pragma unroll
        for (int i = 0; i < 5; ++i) {
            int idx = tid + i * 256;
            if (idx < 1088) {
                int n = idx >> 2, ko = (idx & 3) * 8;
                *(bf16x8*)&Blds[n * 40 + ko] =
                    *(const bf16x8*)&Wo_t[(size_t)n * HH + kt + ko];
            }
        }
        __syncthreads();
        const int m = w * 32;
        bf16x8 af0 = *(const bf16x8*)&Alds[(m + c) * 40 + g * 8];
        bf16x8 af1 = *(const bf16x8*)&Alds[(m + 16 + c) * 40 + g * 8];
#pragma unroll
        for (int j = 0; j < 17; ++j) {
            bf16x8 bv = *(const bf16x8*)&Blds[(j * 16 + c) * 40 + g * 8];
            acc[0][j] = __builtin_amdgcn_mfma_f32_16x16x32_bf16(af0, bv, acc[0][j], 0, 0, 0);
            acc[1][j] = __builtin_amdgcn_mfma_f32_16x16x32_bf16(af1, bv, acc[1][j], 0, 0, 0);
        }
        __syncthreads();
    }

    // epilogue: per row lse over cols 0..256, extract blank (col 0) and label col
#pragma unroll
    for (int mt = 0; mt < 2; ++mt) {
#pragma unroll
        for (int r = 0; r < 4; ++r) {
            int row_in = w * 32 + mt * 16 + g * 4 + r;
            int gr = r0 + row_in;
            int t = gr / NU, u = gr - t * NU;

            float mx = NEG_INF;
#pragma unroll
            for (int j = 0; j < 17; ++j) {
                int col = j * 16 + c;
                if (col < NV) mx = fmaxf(mx, acc[mt][j][r]);
            }
#pragma unroll
            for (int s = 1; s < 16; s <<= 1) mx = fmaxf(mx, __shfl_xor(mx, s));
            float sum = 0.f;
#pragma unroll
            for (int j = 0; j < 17; ++j) {
                int col = j * 16 + c;
                if (col < NV) sum += __expf(acc[mt][j][r] - mx);
            }
#pragma unroll
            for (int s = 1; s < 16; s <<= 1) sum += __shfl_xor(sum, s);
            float lse = mx + __logf(sum);

            float blankv = __shfl(acc[mt][0][r], (lane & 48));  // col 0 from lane g*16

            int colL = (u < UU) ? labels[b * UU + u] : 0;  // 1..256
            int jl = colL >> 4, cl = colL & 15;
            int src = (lane & 48) | cl;
            float lexv = 0.f;
#pragma unroll
            for (int j = 0; j < 17; ++j) {
                float cand = __shfl(acc[mt][j][r], src);
                if (j == jl) lexv = cand;
            }

            if (c == 0) {
                size_t base = ((size_t)b * TT + t) * NU + u;
                blank_arr[base] = blankv - lse;
                if (u < UU) lex_arr[base] = lexv - lse;
            }
        }
    }
}

// ---- forward DP: one wave per batch, alpha in 2 regs/lane ----
__global__ void k_dp(const float* __restrict__ blank_arr,
                     const float* __restrict__ lex_arr,
                     const int* __restrict__ num_frames,
                     const int* __restrict__ num_labels,
                     float* __restrict__ out) {
    const int b = blockIdx.x;
    const int lane = threadIdx.x;
    const int nf = num_frames[b];
    const int nl = num_labels[b];
    const float* Bp = blank_arr + (size_t)b * TT * NU;
    const float* Lp = lex_arr + (size_t)b * TT * NU;

    float a_lo = (lane == 0) ? 0.f : NEG_INF;  // alpha[u=lane]
    float a_hi = NEG_INF;                      // alpha[u=64+lane], lane<33

    // prefetch t=0
    float b_lo = Bp[lane];
    float b_hi = (lane < 33) ? Bp[64 + lane] : NEG_INF;
    float l_lo = Lp[lane];
    float l_hi = (lane < 32) ? Lp[64 + lane] : 0.f;

    for (int t = 0; t < nf; ++t) {
        float nb_lo = 0.f, nb_hi = 0.f, nl_lo = 0.f, nl_hi = 0.f;
        if (t + 1 < nf) {
            const float* Bn = Bp + (size_t)(t + 1) * NU;
            const float* Ln = Lp + (size_t)(t + 1) * NU;
            nb_lo = Bn[lane];
            nb_hi = (lane < 33) ? Bn[64 + lane] : NEG_INF;
            nl_lo = Ln[lane];
            nl_hi = (lane < 32) ? Ln[64 + lane] : 0.f;
        }
        float stay_lo = a_lo + b_lo;
        float ap = __shfl_up(a_lo, 1);
        float lp = __shfl_up(l_lo, 1);
        float emit_lo = (lane == 0) ? NEG_INF : (ap + lp);
        float new_lo = lae(stay_lo, emit_lo);

        float stay_hi = a_hi + b_hi;
        float ap_hi = __shfl_up(a_hi, 1);
        float lp_hi = __shfl_up(l_hi, 1);
        float a63 = __shfl(a_lo, 63);
        float l63 = __shfl(l_lo, 63);
        if (lane == 0) { ap_hi = a63; lp_hi = l63; }
        float new_hi = lae(stay_hi, ap_hi + lp_hi);

        a_lo = new_lo;
        if (lane < 33) a_hi = new_hi;
        b_lo = nb_lo; b_hi = nb_hi; l_lo = nl_lo; l_hi = nl_hi;
    }
    float res = (nl < 64) ? __shfl(a_lo, nl) : __shfl(a_hi, nl - 64);
    if (lane == 0) out[b] = -res;
}

extern "C" void kernel_launch(void* const* d_in, const int* in_sizes, int n_in,
                              void* d_out, int out_size, void* d_ws, size_t ws_size,
                              hipStream_t stream) {
    const float* frames = (const float*)d_in[0];
    const int* num_frames = (const int*)d_in[1];
    const int* labels = (const int*)d_in[2];
    const int* num_labels = (const int*)d_in[3];
    const float* Wf = (const float*)d_in[4];
    const float* E = (const float*)d_in[5];
    const float* Wo = (const float*)d_in[6];
    float* out = (float*)d_out;

    char* ws = (char*)d_ws;
    size_t off = 0;
    bf16* Wf_t = (bf16*)(ws + off); off += (size_t)HH * FF * 2;            // 512 KiB
    bf16* Wo_t = (bf16*)(ws + off); off += (size_t)NPAD * HH * 2;          // 272 KiB
    float* cemb = (float*)(ws + off); off += (size_t)BB * NU * HH * 4;     // 776 KiB
    float* fproj = (float*)(ws + off); off += (size_t)BB * TT * HH * 4;    // 4 MiB
    float* blank_arr = (float*)(ws + off); off += (size_t)BB * TT * NU * 4;
    float* lex_arr = (float*)(ws + off); off += (size_t)BB * TT * NU * 4;
    // total ~7.04 MiB

    hipLaunchKernelGGL(k_wf_t, dim3(HH), dim3(256), 0, stream, Wf, Wf_t);
    hipLaunchKernelGGL(k_wo_t, dim3(NPAD), dim3(256), 0, stream, Wo, Wo_t);
    hipLaunchKernelGGL(k_cemb, dim3(NU, BB), dim3(128), 0, stream, E, labels, cemb);
    hipLaunchKernelGGL(k_fproj, dim3((BB * TT) / 64, HH / 64), dim3(256), 0, stream,
                       frames, Wf_t, fproj);
    hipLaunchKernelGGL(k_joint, dim3((TT * NU) / 128, BB), dim3(256), 0, stream,
                       fproj, cemb, Wo_t, labels, num_frames, blank_arr, lex_arr);
    hipLaunchKernelGGL(k_dp, dim3(BB), dim3(64), 0, stream,
                       blank_arr, lex_arr, num_frames, num_labels, out);
}

// Round 2
// 321.868 us; speedup vs baseline: 1.2344x; 1.2344x over previous
//
#include <hip/hip_runtime.h>
#include <hip/hip_bf16.h>

// RecognitionLattice: RNN-T style lattice loss.
// Pipeline: transpose/cast weights -> cemb gather -> fproj GEMM (bf16 MFMA)
//        -> joint GEMM h=tanh(fproj+cemb), logits=h@Wo, fused logsumexp
//        -> per-batch forward DP (1 wave each, 8-deep load pipeline).

#define BB 4
#define TT 512
#define UU 96
#define FF 512
#define HH 512
#define VV 256
#define NV (VV + 1)    // 257 vocab incl. blank
#define NU (UU + 1)    // 97 lattice rows per t
#define NPAD 272       // 17 * 16, padded N for MFMA
#define NEG_INF (-1e30f)

typedef __bf16 bf16;
typedef __bf16 bf16x8 __attribute__((ext_vector_type(8)));
typedef float f32x4 __attribute__((ext_vector_type(4)));

__device__ __forceinline__ float fast_tanh(float x) {
    float e = __expf(2.0f * x);
    return 1.0f - 2.0f / (e + 1.0f);
}

__device__ __forceinline__ float lae(float x, float y) {
    float m = fmaxf(x, y);
    float d = fminf(x, y) - m;
    return m + __logf(1.0f + __expf(d));
}

// ---- prep: Wf^T cast to bf16: Wf_t[n][k] = Wf[k][n] ----
__global__ void k_wf_t(const float* __restrict__ Wf, bf16* __restrict__ Wf_t) {
    int n = blockIdx.x;
    for (int k = threadIdx.x; k < FF; k += blockDim.x)
        Wf_t[n * FF + k] = (bf16)Wf[k * HH + n];
}

// ---- prep: Wo^T cast to bf16 with zero pad rows: Wo_t[n][k] = Wo[k][n] ----
__global__ void k_wo_t(const float* __restrict__ Wo, bf16* __restrict__ Wo_t) {
    int n = blockIdx.x;  // 0..271
    for (int k = threadIdx.x; k < HH; k += blockDim.x) {
        float v = (n < NV) ? Wo[k * NV + n] : 0.0f;
        Wo_t[n * HH + k] = (bf16)v;
    }
}

// ---- prep: cemb[b][u][:] = E[ctx(b,u)][:] ----
__global__ void k_cemb(const float* __restrict__ E, const int* __restrict__ labels,
                       float* __restrict__ cemb) {
    int u = blockIdx.x;  // 0..96
    int b = blockIdx.y;
    int ctx = (u == 0) ? 0 : labels[b * UU + (u - 1)];
    const float4* src = (const float4*)&E[(size_t)ctx * HH];
    float4* dst = (float4*)&cemb[((size_t)b * NU + u) * HH];
    for (int i = threadIdx.x; i < HH / 4; i += blockDim.x) dst[i] = src[i];
}

// ---- fproj = frames @ Wf  (bf16 MFMA, fp32 out) ----
// grid (2048/64, 512/64), block 256. 64x64 tile, wave = 16 rows x 64 cols.
__global__ __launch_bounds__(256, 2) void k_fproj(
    const float* __restrict__ frames, const bf16* __restrict__ Wf_t,
    float* __restrict__ fproj) {
    __shared__ bf16 Alds[64 * 40];
    __shared__ bf16 Blds[64 * 40];
    const int tid = threadIdx.x;
    const int r0 = blockIdx.x * 64;
    const int n0 = blockIdx.y * 64;
    const int lane = tid & 63, w = tid >> 6;
    const int c = lane & 15, g = lane >> 4;

    const int srow = tid >> 2, sko = (tid & 3) * 8;
    const float* fptr = frames + (size_t)(r0 + srow) * FF + sko;
    const bf16* wptr = Wf_t + (size_t)(n0 + srow) * FF + sko;

    f32x4 acc[4];
#pragma unroll
    for (int j = 0; j < 4; ++j) acc[j] = (f32x4){0.f, 0.f, 0.f, 0.f};

    for (int kt = 0; kt < FF; kt += 32) {
        float4 f1 = *(const float4*)(fptr + kt);
        float4 f2 = *(const float4*)(fptr + kt + 4);
        bf16x8 av = {(bf16)f1.x, (bf16)f1.y, (bf16)f1.z, (bf16)f1.w,
                     (bf16)f2.x, (bf16)f2.y, (bf16)f2.z, (bf16)f2.w};
        *(bf16x8*)&Alds[srow * 40 + sko] = av;
        *(bf16x8*)&Blds[srow * 40 + sko] = *(const bf16x8*)(wptr + kt);
        __syncthreads();
        const int m = w * 16;
        bf16x8 af = *(const bf16x8*)&Alds[(m + c) * 40 + g * 8];
#pragma unroll
        for (int j = 0; j < 4; ++j) {
            bf16x8 bv = *(const bf16x8*)&Blds[(j * 16 + c) * 40 + g * 8];
            acc[j] = __builtin_amdgcn_mfma_f32_16x16x32_bf16(af, bv, acc[j], 0, 0, 0);
        }
        __syncthreads();
    }
    const int m = w * 16;
#pragma unroll
    for (int j = 0; j < 4; ++j)
#pragma unroll
        for (int r = 0; r < 4; ++r)
            fproj[(size_t)(r0 + m + g * 4 + r) * HH + n0 + j * 16 + c] = acc[j][r];
}

// ---- joint: logits = tanh(fproj[t]+cemb[u]) @ Wo, fused log_softmax extract ----
// grid (49664/128, B), block 256. Writes interleaved {blank, lex} per (t,u).
__global__ __launch_bounds__(256, 2) void k_joint(
    const float* __restrict__ fproj, const float* __restrict__ cemb,
    const bf16* __restrict__ Wo_t, const int* __restrict__ labels,
    const int* __restrict__ num_frames,
    float* __restrict__ cl_arr) {
    __shared__ bf16 Alds[128 * 40];   // 10240 B
    __shared__ bf16 Blds[NPAD * 40];  // 21760 B
    const int tid = threadIdx.x;
    const int b = blockIdx.y;
    const int r0 = blockIdx.x * 128;
    const int nf = num_frames[b];
    if (r0 / NU >= nf) return;  // whole tile beyond active frames: outputs unused

    const int lane = tid & 63, w = tid >> 6;
    const int c = lane & 15, g = lane >> 4;

    // A-staging: 128 rows x 32 k per iter = 512 vec8 tasks; 2 per thread
    const float* pfA[2];
    const float* pcA[2];
    int arow[2], ako[2];
#pragma unroll
    for (int i = 0; i < 2; ++i) {
        int idx = tid + i * 256;
        int row = idx >> 2, ko = (idx & 3) * 8;
        int gr = r0 + row;
        int t = gr / NU, u = gr - t * NU;
        arow[i] = row;
        ako[i] = ko;
        pfA[i] = fproj + ((size_t)(b * TT + t)) * HH + ko;
        pcA[i] = cemb + ((size_t)(b * NU + u)) * HH + ko;
    }

    f32x4 acc[2][17];
#pragma unroll
    for (int mt = 0; mt < 2; ++mt)
#pragma unroll
        for (int j = 0; j < 17; ++j) acc[mt][j] = (f32x4){0.f, 0.f, 0.f, 0.f};

    for (int kt = 0; kt < HH; kt += 32) {
#pragma unroll
        for (int i = 0; i < 2; ++i) {
            float4 f1 = *(const float4*)(pfA[i] + kt);
            float4 f2 = *(const float4*)(pfA[i] + kt + 4);
            float4 c1 = *(const float4*)(pcA[i] + kt);
            float4 c2 = *(const float4*)(pcA[i] + kt + 4);
            bf16x8 av = {(bf16)fast_tanh(f1.x + c1.x), (bf16)fast_tanh(f1.y + c1.y),
                         (bf16)fast_tanh(f1.z + c1.z), (bf16)fast_tanh(f1.w + c1.w),
                         (bf16)fast_tanh(f2.x + c2.x), (bf16)fast_tanh(f2.y + c2.y),
                         (bf16)fast_tanh(f2.z + c2.z), (bf16)fast_tanh(f2.w + c2.w)};
            *(bf16x8*)&Alds[arow[i] * 40 + ako[i]] = av;
        }
        // B-staging: 272 rows x 32 k = 1088 vec8 tasks
#pragma unroll
        for (int i = 0; i < 5; ++i) {
            int idx = tid + i * 256;
            if (idx < 1088) {
                int n = idx >> 2, ko = (idx & 3) * 8;
                *(bf16x8*)&Blds[n * 40 + ko] =
                    *(const bf16x8*)&Wo_t[(size_t)n * HH + kt + ko];
            }
        }
        __syncthreads();
        const int m = w * 32;
        bf16x8 af0 = *(const bf16x8*)&Alds[(m + c) * 40 + g * 8];
        bf16x8 af1 = *(const bf16x8*)&Alds[(m + 16 + c) * 40 + g * 8];
#pragma unroll
        for (int j = 0; j < 17; ++j) {
            bf16x8 bv = *(const bf16x8*)&Blds[(j * 16 + c) * 40 + g * 8];
            acc[0][j] = __builtin_amdgcn_mfma_f32_16x16x32_bf16(af0, bv, acc[0][j], 0, 0, 0);
            acc[1][j] = __builtin_amdgcn_mfma_f32_16x16x32_bf16(af1, bv, acc[1][j], 0, 0, 0);
        }
        __syncthreads();
    }

    // epilogue: per row lse over cols 0..256, extract blank (col 0) and label col
#pragma unroll
    for (int mt = 0; mt < 2; ++mt) {
#pragma unroll
        for (int r = 0; r < 4; ++r) {
            int row_in = w * 32 + mt * 16 + g * 4 + r;
            int gr = r0 + row_in;
            int t = gr / NU, u = gr - t * NU;

            float mx = NEG_INF;
#pragma unroll
            for (int j = 0; j < 17; ++j) {
                int col = j * 16 + c;
                if (col < NV) mx = fmaxf(mx, acc[mt][j][r]);
            }
#pragma unroll
            for (int s = 1; s < 16; s <<= 1) mx = fmaxf(mx, __shfl_xor(mx, s));
            float sum = 0.f;
#pragma unroll
            for (int j = 0; j < 17; ++j) {
                int col = j * 16 + c;
                if (col < NV) sum += __expf(acc[mt][j][r] - mx);
            }
#pragma unroll
            for (int s = 1; s < 16; s <<= 1) sum += __shfl_xor(sum, s);
            float lse = mx + __logf(sum);

            float blankv = __shfl(acc[mt][0][r], (lane & 48));  // col 0 from lane g*16

            int colL = (u < UU) ? labels[b * UU + u] : 0;  // 1..256
            int jl = colL >> 4, cl = colL & 15;
            int src = (lane & 48) | cl;
            float lexv = 0.f;
#pragma unroll
            for (int j = 0; j < 17; ++j) {
                float cand = __shfl(acc[mt][j][r], src);
                if (j == jl) lexv = cand;
            }

            if (c == 0) {
                size_t base = (((size_t)b * TT + t) * NU + u) * 2;
                float2 v;
                v.x = blankv - lse;
                v.y = (u < UU) ? (lexv - lse) : 0.f;
                *(float2*)&cl_arr[base] = v;
            }
        }
    }
}

// ---- forward DP: one wave per batch, alpha in 2 regs/lane, 8-deep prefetch ----
__global__ void k_dp(const float* __restrict__ cl,
                     const int* __restrict__ num_frames,
                     const int* __restrict__ num_labels,
                     float* __restrict__ out) {
    const int b = blockIdx.x;
    const int lane = threadIdx.x;
    const int nf = num_frames[b];
    const int nl = num_labels[b];
    const float2* P = (const float2*)(cl + (size_t)b * TT * NU * 2);
    // P[t*NU + u] = {blank, lex} at (t,u)

    float a_lo = (lane == 0) ? 0.f : NEG_INF;  // alpha[u=lane]
    float a_hi = NEG_INF;                      // alpha[u=64+lane], lane<33
    const bool hi_act = (lane < 33);

    constexpr int D = 8;
    float2 buf_lo[D], buf_hi[D];
#pragma unroll
    for (int d = 0; d < D; ++d) {
        buf_lo[d] = P[d * NU + lane];
        buf_hi[d] = hi_act ? P[d * NU + 64 + lane] : make_float2(NEG_INF, 0.f);
    }

#pragma unroll 8
    for (int t = 0; t < TT; ++t) {
        const int slot = t & (D - 1);
        float2 v_lo = buf_lo[slot];
        float2 v_hi = buf_hi[slot];
        int tp = t + D;
        if (tp < TT) {
            buf_lo[slot] = P[tp * NU + lane];
            if (hi_act) buf_hi[slot] = P[tp * NU + 64 + lane];
        }
        // emit source: e[u] = alpha[u] + lex[u]; emit into u+1 via shfl_up
        float e_lo = a_lo + v_lo.y;
        float e_hi = a_hi + v_hi.y;
        float em_lo = __shfl_up(e_lo, 1);
        float em_hi = __shfl_up(e_hi, 1);
        float e63 = __shfl(e_lo, 63);
        if (lane == 0) { em_lo = NEG_INF; em_hi = e63; }
        float new_lo = lae(a_lo + v_lo.x, em_lo);
        float new_hi = lae(a_hi + v_hi.x, em_hi);
        bool act = (t < nf);
        a_lo = act ? new_lo : a_lo;
        if (hi_act) a_hi = act ? new_hi : a_hi;
    }
    float res = (nl < 64) ? __shfl(a_lo, nl) : __shfl(a_hi, nl - 64);
    if (lane == 0) out[b] = -res;
}

extern "C" void kernel_launch(void* const* d_in, const int* in_sizes, int n_in,
                              void* d_out, int out_size, void* d_ws, size_t ws_size,
                              hipStream_t stream) {
    const float* frames = (const float*)d_in[0];
    const int* num_frames = (const int*)d_in[1];
    const int* labels = (const int*)d_in[2];
    const int* num_labels = (const int*)d_in[3];
    const float* Wf = (const float*)d_in[4];
    const float* E = (const float*)d_in[5];
    const float* Wo = (const float*)d_in[6];
    float* out = (float*)d_out;

    char* ws = (char*)d_ws;
    size_t off = 0;
    bf16* Wf_t = (bf16*)(ws + off); off += (size_t)HH * FF * 2;            // 512 KiB
    bf16* Wo_t = (bf16*)(ws + off); off += (size_t)NPAD * HH * 2;          // 272 KiB
    float* cemb = (float*)(ws + off); off += (size_t)BB * NU * HH * 4;     // 776 KiB
    float* fproj = (float*)(ws + off); off += (size_t)BB * TT * HH * 4;    // 4 MiB
    float* cl_arr = (float*)(ws + off); off += (size_t)BB * TT * NU * 2 * 4;  // 1.52 MiB

    hipLaunchKernelGGL(k_wf_t, dim3(HH), dim3(256), 0, stream, Wf, Wf_t);
    hipLaunchKernelGGL(k_wo_t, dim3(NPAD), dim3(256), 0, stream, Wo, Wo_t);
    hipLaunchKernelGGL(k_cemb, dim3(NU, BB), dim3(128), 0, stream, E, labels, cemb);
    hipLaunchKernelGGL(k_fproj, dim3((BB * TT) / 64, HH / 64), dim3(256), 0, stream,
                       frames, Wf_t, fproj);
    hipLaunchKernelGGL(k_joint, dim3((TT * NU) / 128, BB), dim3(256), 0, stream,
                       fproj, cemb, Wo_t, labels, num_frames, cl_arr);
    hipLaunchKernelGGL(k_dp, dim3(BB), dim3(64), 0, stream,
                       cl_arr, num_frames, num_labels, out);
}

// Round 3
// 315.056 us; speedup vs baseline: 1.2611x; 1.0216x over previous
//
#include <hip/hip_runtime.h>
#include <hip/hip_bf16.h>

// RecognitionLattice: RNN-T style lattice loss.
// prep (bf16 weight shuffle) -> cemb gather (bf16) -> fproj GEMM (bf16 out)
// -> joint GEMM h=tanh(fproj+cemb) @ Wo with kg-plane LDS + async B staging,
//    fused logsumexp -> per-batch forward DP (1 wave, 8-deep pipeline).

#define BB 4
#define TT 512
#define UU 96
#define FF 512
#define HH 512
#define VV 256
#define NV (VV + 1)    // 257 vocab incl. blank
#define NU (UU + 1)    // 97 lattice rows per t
#define NP 288         // 18*16 padded N
#define NEG_INF (-1e30f)

typedef __bf16 bf16;
typedef __bf16 bf16x8 __attribute__((ext_vector_type(8)));
typedef float f32x4 __attribute__((ext_vector_type(4)));

__device__ __forceinline__ float fast_tanh(float x) {
    float e = __expf(2.0f * x);
    return 1.0f - 2.0f / (e + 1.0f);
}

__device__ __forceinline__ float lae(float x, float y) {
    float m = fmaxf(x, y);
    float d = fminf(x, y) - m;
    return m + __logf(1.0f + __expf(d));
}

__device__ __forceinline__ void async_copy16(const void* g, void* l) {
    __builtin_amdgcn_global_load_lds(
        (const __attribute__((address_space(1))) unsigned int*)g,
        (__attribute__((address_space(3))) unsigned int*)l, 16, 0, 0);
}

// ---- prep: Wf^T cast to bf16: Wf_t[n][k] = Wf[k][n] ----
__global__ void k_wf_t(const float* __restrict__ Wf, bf16* __restrict__ Wf_t) {
    int n = blockIdx.x;
    for (int k = threadIdx.x; k < FF; k += blockDim.x)
        Wf_t[n * FF + k] = (bf16)Wf[k * HH + n];
}

// ---- prep: Wo_s[k32][kg][n][8] = Wo[k32*32+kg*8+e][n], bf16, n<257 else 0 ----
__global__ void k_wo_s(const float* __restrict__ Wo, bf16* __restrict__ Wo_s) {
    int idx = blockIdx.x * 256 + threadIdx.x;  // 16*4*288 = 18432
    int n = idx % NP;
    int rest = idx / NP;
    int kg = rest & 3;
    int k32 = rest >> 2;
    bf16x8 v;
#pragma unroll
    for (int e = 0; e < 8; ++e) {
        int k = k32 * 32 + kg * 8 + e;
        v[e] = (n < NV) ? (bf16)Wo[k * NV + n] : (bf16)0.f;
    }
    *(bf16x8*)&Wo_s[(size_t)idx * 8] = v;
}

// ---- prep: cemb_bf[b][u][:] = bf16(E[ctx(b,u)][:]) ----
__global__ void k_cemb(const float* __restrict__ E, const int* __restrict__ labels,
                       bf16* __restrict__ cemb) {
    int u = blockIdx.x;  // 0..96
    int b = blockIdx.y;
    int ctx = (u == 0) ? 0 : labels[b * UU + (u - 1)];
    const float* src = E + (size_t)ctx * HH;
    bf16* dst = cemb + ((size_t)b * NU + u) * HH;
    for (int i = threadIdx.x; i < HH; i += blockDim.x) dst[i] = (bf16)src[i];
}

// ---- fproj = frames @ Wf  (bf16 MFMA, bf16 out) ----
__global__ __launch_bounds__(256, 2) void k_fproj(
    const float* __restrict__ frames, const bf16* __restrict__ Wf_t,
    bf16* __restrict__ fproj) {
    __shared__ bf16 Alds[64 * 40];
    __shared__ bf16 Blds[64 * 40];
    const int tid = threadIdx.x;
    const int r0 = blockIdx.x * 64;
    const int n0 = blockIdx.y * 64;
    const int lane = tid & 63, w = tid >> 6;
    const int c = lane & 15, g = lane >> 4;

    const int srow = tid >> 2, sko = (tid & 3) * 8;
    const float* fptr = frames + (size_t)(r0 + srow) * FF + sko;
    const bf16* wptr = Wf_t + (size_t)(n0 + srow) * FF + sko;

    f32x4 acc[4];
#pragma unroll
    for (int j = 0; j < 4; ++j) acc[j] = (f32x4){0.f, 0.f, 0.f, 0.f};

    for (int kt = 0; kt < FF; kt += 32) {
        float4 f1 = *(const float4*)(fptr + kt);
        float4 f2 = *(const float4*)(fptr + kt + 4);
        bf16x8 av = {(bf16)f1.x, (bf16)f1.y, (bf16)f1.z, (bf16)f1.w,
                     (bf16)f2.x, (bf16)f2.y, (bf16)f2.z, (bf16)f2.w};
        *(bf16x8*)&Alds[srow * 40 + sko] = av;
        *(bf16x8*)&Blds[srow * 40 + sko] = *(const bf16x8*)(wptr + kt);
        __syncthreads();
        const int m = w * 16;
        bf16x8 af = *(const bf16x8*)&Alds[(m + c) * 40 + g * 8];
#pragma unroll
        for (int j = 0; j < 4; ++j) {
            bf16x8 bv = *(const bf16x8*)&Blds[(j * 16 + c) * 40 + g * 8];
            acc[j] = __builtin_amdgcn_mfma_f32_16x16x32_bf16(af, bv, acc[j], 0, 0, 0);
        }
        __syncthreads();
    }
    const int m = w * 16;
#pragma unroll
    for (int j = 0; j < 4; ++j)
#pragma unroll
        for (int r = 0; r < 4; ++r)
            fproj[(size_t)(r0 + m + g * 4 + r) * HH + n0 + j * 16 + c] = (bf16)acc[j][r];
}

// ---- joint: logits = tanh(fproj[t]+cemb[u]) @ Wo, fused log_softmax extract ----
// grid (388, B), block 256 = 2x2 waves, wave tile 64x144.
// LDS: A kg-planes (stride 1040 elems for bank rotation), B kg-planes flat
// (filled by global_load_lds, lane-contiguous).
__global__ __launch_bounds__(256, 2) void k_joint(
    const bf16* __restrict__ fproj, const bf16* __restrict__ cemb,
    const bf16* __restrict__ Wo_s, const int* __restrict__ labels,
    const int* __restrict__ num_frames, float* __restrict__ cl_arr) {
    __shared__ bf16 A_s[4 * 1040];   // 8320 B, plane kg at kg*1040 (bank rot kg*8)
    __shared__ bf16 B_s[18 * 512];   // 18432 B flat = kg*2304 + n*8
    __shared__ float red[6 * 128];   // pmax0/1, psum0/1, pblank, plex

    const int tid = threadIdx.x;
    const int b = blockIdx.y;
    const int r0 = blockIdx.x * 128;
    const int nf = num_frames[b];
    if (r0 / NU >= nf) return;  // whole tile beyond active frames: outputs unused

    const int lane = tid & 63, w = tid >> 6;
    const int wm = w & 1, wn = w >> 1;
    const int c = lane & 15, g = lane >> 4;

    // A-staging tasks: 128 rows x 4 kg = 512; thread handles idx = tid, tid+256.
    const bf16* pf[2];
    const bf16* pc[2];
    int sdst[2];
#pragma unroll
    for (int i = 0; i < 2; ++i) {
        int idx = tid + i * 256;
        int row = idx >> 2, kg = idx & 3;
        int gr = r0 + row;
        int t = gr / NU, u = gr - t * NU;
        pf[i] = fproj + ((size_t)(b * TT + t)) * HH + kg * 8;
        pc[i] = cemb + ((size_t)(b * NU + u)) * HH + kg * 8;
        sdst[i] = kg * 1040 + row * 8;
    }
    const bf16* wsrc = Wo_s + (size_t)lane * 8;

    f32x4 acc[4][9];
#pragma unroll
    for (int mt = 0; mt < 4; ++mt)
#pragma unroll
        for (int j = 0; j < 9; ++j) acc[mt][j] = (f32x4){0.f, 0.f, 0.f, 0.f};

    const int aBase = g * 1040 + (wm * 64 + c) * 8;
    const int bBase = g * 2304 + (wn * 144 + c) * 8;

    for (int k32 = 0; k32 < 16; ++k32) {
        // async B stage: 18 chunks of 1 KiB, lane-contiguous dest
        const bf16* wk = wsrc + (size_t)k32 * 9216;
        for (int ch = w; ch < 18; ch += 4)
            async_copy16(wk + ch * 512, &B_s[ch * 512 + lane * 8]);
        // A stage: tanh(fproj+cemb) -> bf16
        const int kt = k32 * 32;
#pragma unroll
        for (int i = 0; i < 2; ++i) {
            bf16x8 fv = *(const bf16x8*)(pf[i] + kt);
            bf16x8 cv = *(const bf16x8*)(pc[i] + kt);
            bf16x8 av;
#pragma unroll
            for (int e = 0; e < 8; ++e)
                av[e] = (bf16)fast_tanh((float)fv[e] + (float)cv[e]);
            *(bf16x8*)&A_s[sdst[i]] = av;
        }
        __syncthreads();
        bf16x8 af[4];
#pragma unroll
        for (int mt = 0; mt < 4; ++mt)
            af[mt] = *(const bf16x8*)&A_s[aBase + mt * 128];
#pragma unroll
        for (int j = 0; j < 9; ++j) {
            bf16x8 bv = *(const bf16x8*)&B_s[bBase + j * 128];
#pragma unroll
            for (int mt = 0; mt < 4; ++mt)
                acc[mt][j] = __builtin_amdgcn_mfma_f32_16x16x32_bf16(af[mt], bv, acc[mt][j], 0, 0, 0);
        }
        __syncthreads();
    }

    // epilogue: per-wave partial lse over owned 144 cols, cross-wave combine in LDS
    float* pmax0 = red;
    float* pmax1 = red + 128;
    float* psum0 = red + 256;
    float* psum1 = red + 384;
    float* pblank = red + 512;
    float* plex = red + 640;

#pragma unroll
    for (int mt = 0; mt < 4; ++mt) {
#pragma unroll
        for (int r = 0; r < 4; ++r) {
            int row_in = wm * 64 + mt * 16 + g * 4 + r;
            int gr = r0 + row_in;
            int t = gr / NU, u = gr - t * NU;
            (void)t;

            float mx = NEG_INF;
#pragma unroll
            for (int j = 0; j < 9; ++j) {
                int col = wn * 144 + j * 16 + c;
                if (col < NV) mx = fmaxf(mx, acc[mt][j][r]);
            }
#pragma unroll
            for (int s = 1; s < 16; s <<= 1) mx = fmaxf(mx, __shfl_xor(mx, s));
            float sum = 0.f;
#pragma unroll
            for (int j = 0; j < 9; ++j) {
                int col = wn * 144 + j * 16 + c;
                if (col < NV) sum += __expf(acc[mt][j][r] - mx);
            }
#pragma unroll
            for (int s = 1; s < 16; s <<= 1) sum += __shfl_xor(sum, s);

            int L = (u < UU) ? labels[b * UU + u] : -1;  // 1..256 or -1
            int lc = L - wn * 144;
            bool own = (lc >= 0) && (lc < 144);
            int src = (lane & 48) | (lc & 15);
            int jl = lc >> 4;
            float lexv = 0.f;
#pragma unroll
            for (int j = 0; j < 9; ++j) {
                float cand = __shfl(acc[mt][j][r], src);
                if (j == jl) lexv = cand;
            }
            float blankv = __shfl(acc[mt][0][r], lane & 48);  // col 0 (valid for wn==0)

            if (c == 0) {
                if (wn == 0) {
                    pmax0[row_in] = mx;
                    psum0[row_in] = sum;
                    pblank[row_in] = blankv;
                } else {
                    pmax1[row_in] = mx;
                    psum1[row_in] = sum;
                }
                if (own) plex[row_in] = lexv;
            }
        }
    }
    __syncthreads();
    if (tid < 128) {
        int gr = r0 + tid;
        int t = gr / NU, u = gr - t * NU;
        float m0 = pmax0[tid], m1 = pmax1[tid];
        float mx = fmaxf(m0, m1);
        float s = psum0[tid] * __expf(m0 - mx) + psum1[tid] * __expf(m1 - mx);
        float lse = mx + __logf(s);
        float2 v;
        v.x = pblank[tid] - lse;
        v.y = (u < UU) ? (plex[tid] - lse) : 0.f;
        *(float2*)&cl_arr[(((size_t)b * TT + t) * NU + u) * 2] = v;
    }
}

// ---- forward DP: one wave per batch, alpha in 2 regs/lane, 8-deep prefetch ----
__global__ void k_dp(const float* __restrict__ cl,
                     const int* __restrict__ num_frames,
                     const int* __restrict__ num_labels,
                     float* __restrict__ out) {
    const int b = blockIdx.x;
    const int lane = threadIdx.x;
    const int nf = num_frames[b];
    const int nl = num_labels[b];
    const float2* P = (const float2*)(cl + (size_t)b * TT * NU * 2);

    float a_lo = (lane == 0) ? 0.f : NEG_INF;
    float a_hi = NEG_INF;
    const bool hi_act = (lane < 33);

    constexpr int D = 8;
    float2 buf_lo[D], buf_hi[D];
#pragma unroll
    for (int d = 0; d < D; ++d) {
        buf_lo[d] = P[d * NU + lane];
        buf_hi[d] = hi_act ? P[d * NU + 64 + lane] : make_float2(NEG_INF, 0.f);
    }

#pragma unroll 8
    for (int t = 0; t < TT; ++t) {
        const int slot = t & (D - 1);
        float2 v_lo = buf_lo[slot];
        float2 v_hi = buf_hi[slot];
        int tp = t + D;
        if (tp < TT) {
            buf_lo[slot] = P[tp * NU + lane];
            if (hi_act) buf_hi[slot] = P[tp * NU + 64 + lane];
        }
        float e_lo = a_lo + v_lo.y;
        float e_hi = a_hi + v_hi.y;
        float em_lo = __shfl_up(e_lo, 1);
        float em_hi = __shfl_up(e_hi, 1);
        float e63 = __shfl(e_lo, 63);
        if (lane == 0) { em_lo = NEG_INF; em_hi = e63; }
        float new_lo = lae(a_lo + v_lo.x, em_lo);
        float new_hi = lae(a_hi + v_hi.x, em_hi);
        bool act = (t < nf);
        a_lo = act ? new_lo : a_lo;
        if (hi_act) a_hi = act ? new_hi : a_hi;
    }
    float res = (nl < 64) ? __shfl(a_lo, nl) : __shfl(a_hi, nl - 64);
    if (lane == 0) out[b] = -res;
}

extern "C" void kernel_launch(void* const* d_in, const int* in_sizes, int n_in,
                              void* d_out, int out_size, void* d_ws, size_t ws_size,
                              hipStream_t stream) {
    const float* frames = (const float*)d_in[0];
    const int* num_frames = (const int*)d_in[1];
    const int* labels = (const int*)d_in[2];
    const int* num_labels = (const int*)d_in[3];
    const float* Wf = (const float*)d_in[4];
    const float* E = (const float*)d_in[5];
    const float* Wo = (const float*)d_in[6];
    float* out = (float*)d_out;

    char* ws = (char*)d_ws;
    size_t off = 0;
    bf16* Wf_t = (bf16*)(ws + off); off += (size_t)HH * FF * 2;               // 512 KiB
    bf16* Wo_s = (bf16*)(ws + off); off += (size_t)16 * 9216 * 2;             // 288 KiB
    bf16* cemb = (bf16*)(ws + off); off += (size_t)BB * NU * HH * 2;          // 388 KiB
    off = (off + 255) & ~(size_t)255;
    bf16* fproj = (bf16*)(ws + off); off += (size_t)BB * TT * HH * 2;         // 2 MiB
    off = (off + 255) & ~(size_t)255;
    float* cl_arr = (float*)(ws + off); off += (size_t)BB * TT * NU * 2 * 4;  // 1.52 MiB

    hipLaunchKernelGGL(k_wf_t, dim3(HH), dim3(256), 0, stream, Wf, Wf_t);
    hipLaunchKernelGGL(k_wo_s, dim3(72), dim3(256), 0, stream, Wo, Wo_s);
    hipLaunchKernelGGL(k_cemb, dim3(NU, BB), dim3(128), 0, stream, E, labels, cemb);
    hipLaunchKernelGGL(k_fproj, dim3((BB * TT) / 64, HH / 64), dim3(256), 0, stream,
                       frames, Wf_t, fproj);
    hipLaunchKernelGGL(k_joint, dim3((TT * NU) / 128, BB), dim3(256), 0, stream,
                       fproj, cemb, Wo_s, labels, num_frames, cl_arr);
    hipLaunchKernelGGL(k_dp, dim3(BB), dim3(64), 0, stream,
                       cl_arr, num_frames, num_labels, out);
}

// Round 4
// 308.139 us; speedup vs baseline: 1.2894x; 1.0224x over previous
//
#include <hip/hip_runtime.h>
#include <hip/hip_bf16.h>

// RecognitionLattice: RNN-T style lattice loss.
// k_prep (fused weight shuffles + cemb gather) -> k_fproj GEMM (bf16 out)
// -> k_joint: h=tanh(fproj+cemb) @ Wo, dbuf single-barrier K-loop, fused LSE
// -> k_dp forward DP (1 wave/batch, 8-deep pipeline).

#define BB 4
#define TT 512
#define UU 96
#define FF 512
#define HH 512
#define VV 256
#define NV (VV + 1)    // 257 vocab incl. blank
#define NU (UU + 1)    // 97 lattice rows per t
#define NP 288         // 18*16 padded N
#define NEG_INF (-1e30f)

typedef __bf16 bf16;
typedef __bf16 bf16x8 __attribute__((ext_vector_type(8)));
typedef float f32x4 __attribute__((ext_vector_type(4)));

__device__ __forceinline__ float fast_tanh(float x) {
    float e = __expf(2.0f * x);
    return 1.0f - 2.0f / (e + 1.0f);
}

__device__ __forceinline__ float lae(float x, float y) {
    float m = fmaxf(x, y);
    float d = fminf(x, y) - m;
    return m + __logf(1.0f + __expf(d));
}

__device__ __forceinline__ void async_copy16(const void* g, void* l) {
    __builtin_amdgcn_global_load_lds(
        (const __attribute__((address_space(1))) unsigned int*)g,
        (__attribute__((address_space(3))) unsigned int*)l, 16, 0, 0);
}

// ---- fused prep:
// blk [0,512):      Wf_t[n][k] = bf16(Wf[k][n])
// blk [512,584):    Wo_s[k32][kg][n][8] = bf16(Wo[k32*32+kg*8+e][n]) (n<257 else 0)
// blk [584,681):    cemb[b][u][:] = bf16(E[ctx(b,u)][:])
__global__ void k_prep(const float* __restrict__ Wf, const float* __restrict__ Wo,
                       const float* __restrict__ E, const int* __restrict__ labels,
                       bf16* __restrict__ Wf_t, bf16* __restrict__ Wo_s,
                       bf16* __restrict__ cemb) {
    const int blk = blockIdx.x;
    const int tid = threadIdx.x;
    if (blk < 512) {
        int n = blk;
        for (int k = tid; k < FF; k += 256)
            Wf_t[n * FF + k] = (bf16)Wf[k * HH + n];
    } else if (blk < 584) {
        int idx = (blk - 512) * 256 + tid;  // 0..18431
        int n = idx % NP;
        int rest = idx / NP;
        int kg = rest & 3;
        int k32 = rest >> 2;
        bf16x8 v;
#pragma unroll
        for (int e = 0; e < 8; ++e) {
            int k = k32 * 32 + kg * 8 + e;
            v[e] = (n < NV) ? (bf16)Wo[k * NV + n] : (bf16)0.f;
        }
        *(bf16x8*)&Wo_s[(size_t)idx * 8] = v;
    } else {
        int u = blk - 584;  // 0..96
        for (int b = 0; b < BB; ++b) {
            int ctx = (u == 0) ? 0 : labels[b * UU + (u - 1)];
            const float* src = E + (size_t)ctx * HH;
            bf16* dst = cemb + ((size_t)b * NU + u) * HH;
            for (int i = tid; i < HH; i += 256) dst[i] = (bf16)src[i];
        }
    }
}

// ---- fproj = frames @ Wf  (bf16 MFMA, bf16 out) ----
__global__ __launch_bounds__(256, 2) void k_fproj(
    const float* __restrict__ frames, const bf16* __restrict__ Wf_t,
    bf16* __restrict__ fproj) {
    __shared__ bf16 Alds[64 * 40];
    __shared__ bf16 Blds[64 * 40];
    const int tid = threadIdx.x;
    const int r0 = blockIdx.x * 64;
    const int n0 = blockIdx.y * 64;
    const int lane = tid & 63, w = tid >> 6;
    const int c = lane & 15, g = lane >> 4;

    const int srow = tid >> 2, sko = (tid & 3) * 8;
    const float* fptr = frames + (size_t)(r0 + srow) * FF + sko;
    const bf16* wptr = Wf_t + (size_t)(n0 + srow) * FF + sko;

    f32x4 acc[4];
#pragma unroll
    for (int j = 0; j < 4; ++j) acc[j] = (f32x4){0.f, 0.f, 0.f, 0.f};

    for (int kt = 0; kt < FF; kt += 32) {
        float4 f1 = *(const float4*)(fptr + kt);
        float4 f2 = *(const float4*)(fptr + kt + 4);
        bf16x8 av = {(bf16)f1.x, (bf16)f1.y, (bf16)f1.z, (bf16)f1.w,
                     (bf16)f2.x, (bf16)f2.y, (bf16)f2.z, (bf16)f2.w};
        *(bf16x8*)&Alds[srow * 40 + sko] = av;
        *(bf16x8*)&Blds[srow * 40 + sko] = *(const bf16x8*)(wptr + kt);
        __syncthreads();
        const int m = w * 16;
        bf16x8 af = *(const bf16x8*)&Alds[(m + c) * 40 + g * 8];
#pragma unroll
        for (int j = 0; j < 4; ++j) {
            bf16x8 bv = *(const bf16x8*)&Blds[(j * 16 + c) * 40 + g * 8];
            acc[j] = __builtin_amdgcn_mfma_f32_16x16x32_bf16(af, bv, acc[j], 0, 0, 0);
        }
        __syncthreads();
    }
    const int m = w * 16;
#pragma unroll
    for (int j = 0; j < 4; ++j)
#pragma unroll
        for (int r = 0; r < 4; ++r)
            fproj[(size_t)(r0 + m + g * 4 + r) * HH + n0 + j * 16 + c] = (bf16)acc[j][r];
}

// ---- joint: logits = tanh(fproj[t]+cemb[u]) @ Wo, fused log_softmax extract ----
// grid (388, B), block 256 = 2x2 waves, wave tile 64x144.
// Double-buffered A (tanh-staged) and B (global_load_lds), ONE barrier/iter:
//   iter i: [prefetch A(i+1) regs] [frag reads + MFMA on buf cur]
//           [issue B(i+1) async -> buf nxt] [tanh A(i+1) -> buf nxt] [barrier]
__global__ __launch_bounds__(256, 2) void k_joint(
    const bf16* __restrict__ fproj, const bf16* __restrict__ cemb,
    const bf16* __restrict__ Wo_s, const int* __restrict__ labels,
    const int* __restrict__ num_frames, float* __restrict__ cl_arr) {
    __shared__ bf16 A_s[2][4 * 1040];   // 2 x 8320 B, kg-plane stride 1040 (bank rot)
    __shared__ bf16 B_s[2][18 * 512];   // 2 x 18432 B, flat [kg][n][8]
    __shared__ float red[6 * 128];      // cross-wave LSE combine

    const int tid = threadIdx.x;
    const int b = blockIdx.y;
    const int r0 = blockIdx.x * 128;
    const int nf = num_frames[b];
    if (r0 / NU >= nf) return;  // whole tile beyond active frames: outputs unused

    const int lane = tid & 63, w = tid >> 6;
    const int wm = w & 1, wn = w >> 1;
    const int c = lane & 15, g = lane >> 4;

    // A-staging tasks: 128 rows x 4 kg = 512; thread handles idx = tid, tid+256.
    const bf16* pf[2];
    const bf16* pc[2];
    int sdst[2];
#pragma unroll
    for (int i = 0; i < 2; ++i) {
        int idx = tid + i * 256;
        int row = idx >> 2, kg = idx & 3;
        int gr = r0 + row;
        int t = gr / NU, u = gr - t * NU;
        pf[i] = fproj + ((size_t)(b * TT + t)) * HH + kg * 8;
        pc[i] = cemb + ((size_t)(b * NU + u)) * HH + kg * 8;
        sdst[i] = kg * 1040 + row * 8;
    }
    const bf16* wsrc = Wo_s + (size_t)lane * 8;

    f32x4 acc[4][9];
#pragma unroll
    for (int mt = 0; mt < 4; ++mt)
#pragma unroll
        for (int j = 0; j < 9; ++j) acc[mt][j] = (f32x4){0.f, 0.f, 0.f, 0.f};

    const int aBase = g * 1040 + (wm * 64 + c) * 8;
    const int bBase = g * 2304 + (wn * 144 + c) * 8;

    // ---- prologue: stage k32=0 into buffer 0 ----
    {
        for (int ch = w; ch < 18; ch += 4)
            async_copy16(wsrc + ch * 512, &B_s[0][ch * 512 + lane * 8]);
#pragma unroll
        for (int i = 0; i < 2; ++i) {
            bf16x8 fv = *(const bf16x8*)(pf[i]);
            bf16x8 cv = *(const bf16x8*)(pc[i]);
            bf16x8 av;
#pragma unroll
            for (int e = 0; e < 8; ++e)
                av[e] = (bf16)fast_tanh((float)fv[e] + (float)cv[e]);
            *(bf16x8*)&A_s[0][sdst[i]] = av;
        }
        __syncthreads();
    }

    // ---- main loop: one barrier per k32 ----
    for (int i = 0; i < 16; ++i) {
        const int cur = i & 1, nxt = cur ^ 1;
        // A-register prefetch for i+1 (global->VGPR, consumed after MFMA phase)
        bf16x8 fv2[2], cv2[2];
        if (i < 15) {
            const int kt = (i + 1) * 32;
#pragma unroll
            for (int j = 0; j < 2; ++j) {
                fv2[j] = *(const bf16x8*)(pf[j] + kt);
                cv2[j] = *(const bf16x8*)(pc[j] + kt);
            }
        }
        // MFMA phase on buffers [cur]
        bf16x8 af[4];
#pragma unroll
        for (int mt = 0; mt < 4; ++mt)
            af[mt] = *(const bf16x8*)&A_s[cur][aBase + mt * 128];
#pragma unroll
        for (int j = 0; j < 9; ++j) {
            bf16x8 bv = *(const bf16x8*)&B_s[cur][bBase + j * 128];
#pragma unroll
            for (int mt = 0; mt < 4; ++mt)
                acc[mt][j] = __builtin_amdgcn_mfma_f32_16x16x32_bf16(af[mt], bv, acc[mt][j], 0, 0, 0);
        }
        if (i < 15) {
            // B async stage for i+1 into [nxt] (drained at the barrier below)
            const bf16* wk = wsrc + (size_t)(i + 1) * 9216;
            for (int ch = w; ch < 18; ch += 4)
                async_copy16(wk + ch * 512, &B_s[nxt][ch * 512 + lane * 8]);
            // tanh-stage A(i+1) into [nxt]
#pragma unroll
            for (int j = 0; j < 2; ++j) {
                bf16x8 av;
#pragma unroll
                for (int e = 0; e < 8; ++e)
                    av[e] = (bf16)fast_tanh((float)fv2[j][e] + (float)cv2[j][e]);
                *(bf16x8*)&A_s[nxt][sdst[j]] = av;
            }
        }
        __syncthreads();
    }

    // epilogue: per-wave partial lse over owned 144 cols, cross-wave combine in LDS
    float* pmax0 = red;
    float* pmax1 = red + 128;
    float* psum0 = red + 256;
    float* psum1 = red + 384;
    float* pblank = red + 512;
    float* plex = red + 640;

#pragma unroll
    for (int mt = 0; mt < 4; ++mt) {
#pragma unroll
        for (int r = 0; r < 4; ++r) {
            int row_in = wm * 64 + mt * 16 + g * 4 + r;
            int gr = r0 + row_in;
            int t = gr / NU, u = gr - t * NU;
            (void)t;

            float mx = NEG_INF;
#pragma unroll
            for (int j = 0; j < 9; ++j) {
                int col = wn * 144 + j * 16 + c;
                if (col < NV) mx = fmaxf(mx, acc[mt][j][r]);
            }
#pragma unroll
            for (int s = 1; s < 16; s <<= 1) mx = fmaxf(mx, __shfl_xor(mx, s));
            float sum = 0.f;
#pragma unroll
            for (int j = 0; j < 9; ++j) {
                int col = wn * 144 + j * 16 + c;
                if (col < NV) sum += __expf(acc[mt][j][r] - mx);
            }
#pragma unroll
            for (int s = 1; s < 16; s <<= 1) sum += __shfl_xor(sum, s);

            int L = (u < UU) ? labels[b * UU + u] : -1;  // 1..256 or -1
            int lc = L - wn * 144;
            bool own = (lc >= 0) && (lc < 144);
            int src = (lane & 48) | (lc & 15);
            int jl = lc >> 4;
            float lexv = 0.f;
#pragma unroll
            for (int j = 0; j < 9; ++j) {
                float cand = __shfl(acc[mt][j][r], src);
                if (j == jl) lexv = cand;
            }
            float blankv = __shfl(acc[mt][0][r], lane & 48);  // col 0 (valid for wn==0)

            if (c == 0) {
                if (wn == 0) {
                    pmax0[row_in] = mx;
                    psum0[row_in] = sum;
                    pblank[row_in] = blankv;
                } else {
                    pmax1[row_in] = mx;
                    psum1[row_in] = sum;
                }
                if (own) plex[row_in] = lexv;
            }
        }
    }
    __syncthreads();
    if (tid < 128) {
        int gr = r0 + tid;
        int t = gr / NU, u = gr - t * NU;
        float m0 = pmax0[tid], m1 = pmax1[tid];
        float mx = fmaxf(m0, m1);
        float s = psum0[tid] * __expf(m0 - mx) + psum1[tid] * __expf(m1 - mx);
        float lse = mx + __logf(s);
        float2 v;
        v.x = pblank[tid] - lse;
        v.y = (u < UU) ? (plex[tid] - lse) : 0.f;
        *(float2*)&cl_arr[(((size_t)b * TT + t) * NU + u) * 2] = v;
    }
}

// ---- forward DP: one wave per batch, alpha in 2 regs/lane, 8-deep prefetch ----
__global__ void k_dp(const float* __restrict__ cl,
                     const int* __restrict__ num_frames,
                     const int* __restrict__ num_labels,
                     float* __restrict__ out) {
    const int b = blockIdx.x;
    const int lane = threadIdx.x;
    const int nf = num_frames[b];
    const int nl = num_labels[b];
    const float2* P = (const float2*)(cl + (size_t)b * TT * NU * 2);

    float a_lo = (lane == 0) ? 0.f : NEG_INF;
    float a_hi = NEG_INF;
    const bool hi_act = (lane < 33);

    constexpr int D = 8;
    float2 buf_lo[D], buf_hi[D];
#pragma unroll
    for (int d = 0; d < D; ++d) {
        buf_lo[d] = P[d * NU + lane];
        buf_hi[d] = hi_act ? P[d * NU + 64 + lane] : make_float2(NEG_INF, 0.f);
    }

#pragma unroll 8
    for (int t = 0; t < TT; ++t) {
        const int slot = t & (D - 1);
        float2 v_lo = buf_lo[slot];
        float2 v_hi = buf_hi[slot];
        int tp = t + D;
        if (tp < TT) {
            buf_lo[slot] = P[tp * NU + lane];
            if (hi_act) buf_hi[slot] = P[tp * NU + 64 + lane];
        }
        float e_lo = a_lo + v_lo.y;
        float e_hi = a_hi + v_hi.y;
        float em_lo = __shfl_up(e_lo, 1);
        float em_hi = __shfl_up(e_hi, 1);
        float e63 = __shfl(e_lo, 63);
        if (lane == 0) { em_lo = NEG_INF; em_hi = e63; }
        float new_lo = lae(a_lo + v_lo.x, em_lo);
        float new_hi = lae(a_hi + v_hi.x, em_hi);
        bool act = (t < nf);
        a_lo = act ? new_lo : a_lo;
        if (hi_act) a_hi = act ? new_hi : a_hi;
    }
    float res = (nl < 64) ? __shfl(a_lo, nl) : __shfl(a_hi, nl - 64);
    if (lane == 0) out[b] = -res;
}

extern "C" void kernel_launch(void* const* d_in, const int* in_sizes, int n_in,
                              void* d_out, int out_size, void* d_ws, size_t ws_size,
                              hipStream_t stream) {
    const float* frames = (const float*)d_in[0];
    const int* num_frames = (const int*)d_in[1];
    const int* labels = (const int*)d_in[2];
    const int* num_labels = (const int*)d_in[3];
    const float* Wf = (const float*)d_in[4];
    const float* E = (const float*)d_in[5];
    const float* Wo = (const float*)d_in[6];
    float* out = (float*)d_out;

    char* ws = (char*)d_ws;
    size_t off = 0;
    bf16* Wf_t = (bf16*)(ws + off); off += (size_t)HH * FF * 2;               // 512 KiB
    bf16* Wo_s = (bf16*)(ws + off); off += (size_t)16 * 9216 * 2;             // 288 KiB
    bf16* cemb = (bf16*)(ws + off); off += (size_t)BB * NU * HH * 2;          // 388 KiB
    off = (off + 255) & ~(size_t)255;
    bf16* fproj = (bf16*)(ws + off); off += (size_t)BB * TT * HH * 2;         // 2 MiB
    off = (off + 255) & ~(size_t)255;
    float* cl_arr = (float*)(ws + off); off += (size_t)BB * TT * NU * 2 * 4;  // 1.52 MiB

    hipLaunchKernelGGL(k_prep, dim3(681), dim3(256), 0, stream,
                       Wf, Wo, E, labels, Wf_t, Wo_s, cemb);
    hipLaunchKernelGGL(k_fproj, dim3((BB * TT) / 64, HH / 64), dim3(256), 0, stream,
                       frames, Wf_t, fproj);
    hipLaunchKernelGGL(k_joint, dim3((TT * NU) / 128, BB), dim3(256), 0, stream,
                       fproj, cemb, Wo_s, labels, num_frames, cl_arr);
    hipLaunchKernelGGL(k_dp, dim3(BB), dim3(64), 0, stream,
                       cl_arr, num_frames, num_labels, out);
}

// Round 5
// 290.626 us; speedup vs baseline: 1.3671x; 1.0603x over previous
//
#include <hip/hip_runtime.h>
#include <hip/hip_bf16.h>

// RecognitionLattice: RNN-T style lattice loss.
// k_prep (fused weight shuffles + cemb gather) -> k_fproj GEMM (bf16 out)
// -> k_joint: h=tanh(fproj+cemb) @ Wo, dbuf single-barrier K-loop, fused LSE
// -> k_dp forward DP (1 wave/batch, 8-deep pipeline).

#define BB 4
#define TT 512
#define UU 96
#define FF 512
#define HH 512
#define VV 256
#define NV (VV + 1)    // 257 vocab incl. blank
#define NU (UU + 1)    // 97 lattice rows per t
#define NP 288         // 18*16 padded N
#define NEG_INF (-1e30f)

typedef __bf16 bf16;
typedef __bf16 bf16x8 __attribute__((ext_vector_type(8)));
typedef float f32x4 __attribute__((ext_vector_type(4)));

// tanh via hw exp2 + hw rcp: avoids the IEEE div expansion (~12 VALU ops)
// that dominated VALUBusy in rounds 2-4. 2/log2(e) scaling folded into one mul.
__device__ __forceinline__ float fast_tanh(float x) {
    float e = __builtin_amdgcn_exp2f(x * 2.8853900817779268f);  // exp(2x)
    float r = __builtin_amdgcn_rcpf(e + 1.0f);
    return __builtin_fmaf(-2.0f, r, 1.0f);
}

__device__ __forceinline__ float lae(float x, float y) {
    float m = fmaxf(x, y);
    float d = fminf(x, y) - m;
    return m + __logf(1.0f + __expf(d));
}

__device__ __forceinline__ void async_copy16(const void* g, void* l) {
    __builtin_amdgcn_global_load_lds(
        (const __attribute__((address_space(1))) unsigned int*)g,
        (__attribute__((address_space(3))) unsigned int*)l, 16, 0, 0);
}

// ---- fused prep:
// blk [0,512):      Wf_t[n][k] = bf16(Wf[k][n])
// blk [512,584):    Wo_s[k32][kg][n][8] = bf16(Wo[k32*32+kg*8+e][n]) (n<257 else 0)
// blk [584,681):    cemb[b][u][:] = bf16(E[ctx(b,u)][:])
__global__ void k_prep(const float* __restrict__ Wf, const float* __restrict__ Wo,
                       const float* __restrict__ E, const int* __restrict__ labels,
                       bf16* __restrict__ Wf_t, bf16* __restrict__ Wo_s,
                       bf16* __restrict__ cemb) {
    const int blk = blockIdx.x;
    const int tid = threadIdx.x;
    if (blk < 512) {
        int n = blk;
        for (int k = tid; k < FF; k += 256)
            Wf_t[n * FF + k] = (bf16)Wf[k * HH + n];
    } else if (blk < 584) {
        int idx = (blk - 512) * 256 + tid;  // 0..18431
        int n = idx % NP;
        int rest = idx / NP;
        int kg = rest & 3;
        int k32 = rest >> 2;
        bf16x8 v;
#pragma unroll
        for (int e = 0; e < 8; ++e) {
            int k = k32 * 32 + kg * 8 + e;
            v[e] = (n < NV) ? (bf16)Wo[k * NV + n] : (bf16)0.f;
        }
        *(bf16x8*)&Wo_s[(size_t)idx * 8] = v;
    } else {
        int u = blk - 584;  // 0..96
        for (int b = 0; b < BB; ++b) {
            int ctx = (u == 0) ? 0 : labels[b * UU + (u - 1)];
            const float* src = E + (size_t)ctx * HH;
            bf16* dst = cemb + ((size_t)b * NU + u) * HH;
            for (int i = tid; i < HH; i += 256) dst[i] = (bf16)src[i];
        }
    }
}

// ---- fproj = frames @ Wf  (bf16 MFMA, bf16 out) ----
__global__ __launch_bounds__(256, 2) void k_fproj(
    const float* __restrict__ frames, const bf16* __restrict__ Wf_t,
    bf16* __restrict__ fproj) {
    __shared__ bf16 Alds[64 * 40];
    __shared__ bf16 Blds[64 * 40];
    const int tid = threadIdx.x;
    const int r0 = blockIdx.x * 64;
    const int n0 = blockIdx.y * 64;
    const int lane = tid & 63, w = tid >> 6;
    const int c = lane & 15, g = lane >> 4;

    const int srow = tid >> 2, sko = (tid & 3) * 8;
    const float* fptr = frames + (size_t)(r0 + srow) * FF + sko;
    const bf16* wptr = Wf_t + (size_t)(n0 + srow) * FF + sko;

    f32x4 acc[4];
#pragma unroll
    for (int j = 0; j < 4; ++j) acc[j] = (f32x4){0.f, 0.f, 0.f, 0.f};

    for (int kt = 0; kt < FF; kt += 32) {
        float4 f1 = *(const float4*)(fptr + kt);
        float4 f2 = *(const float4*)(fptr + kt + 4);
        bf16x8 av = {(bf16)f1.x, (bf16)f1.y, (bf16)f1.z, (bf16)f1.w,
                     (bf16)f2.x, (bf16)f2.y, (bf16)f2.z, (bf16)f2.w};
        *(bf16x8*)&Alds[srow * 40 + sko] = av;
        *(bf16x8*)&Blds[srow * 40 + sko] = *(const bf16x8*)(wptr + kt);
        __syncthreads();
        const int m = w * 16;
        bf16x8 af = *(const bf16x8*)&Alds[(m + c) * 40 + g * 8];
#pragma unroll
        for (int j = 0; j < 4; ++j) {
            bf16x8 bv = *(const bf16x8*)&Blds[(j * 16 + c) * 40 + g * 8];
            acc[j] = __builtin_amdgcn_mfma_f32_16x16x32_bf16(af, bv, acc[j], 0, 0, 0);
        }
        __syncthreads();
    }
    const int m = w * 16;
#pragma unroll
    for (int j = 0; j < 4; ++j)
#pragma unroll
        for (int r = 0; r < 4; ++r)
            fproj[(size_t)(r0 + m + g * 4 + r) * HH + n0 + j * 16 + c] = (bf16)acc[j][r];
}

// ---- joint: logits = tanh(fproj[t]+cemb[u]) @ Wo, fused log_softmax extract ----
// grid (388, B), block 256 = 2x2 waves, wave tile 64x144.
// Double-buffered A (tanh-staged) and B (global_load_lds), ONE barrier/iter.
__global__ __launch_bounds__(256, 2) void k_joint(
    const bf16* __restrict__ fproj, const bf16* __restrict__ cemb,
    const bf16* __restrict__ Wo_s, const int* __restrict__ labels,
    const int* __restrict__ num_frames, float* __restrict__ cl_arr) {
    __shared__ bf16 A_s[2][4 * 1040];   // 2 x 8320 B, kg-plane stride 1040 (bank rot)
    __shared__ bf16 B_s[2][18 * 512];   // 2 x 18432 B, flat [kg][n][8]
    __shared__ float red[6 * 128];      // cross-wave LSE combine

    const int tid = threadIdx.x;
    const int b = blockIdx.y;
    const int r0 = blockIdx.x * 128;
    const int nf = num_frames[b];
    if (r0 / NU >= nf) return;  // whole tile beyond active frames: outputs unused

    const int lane = tid & 63, w = tid >> 6;
    const int wm = w & 1, wn = w >> 1;
    const int c = lane & 15, g = lane >> 4;

    // A-staging tasks: 128 rows x 4 kg = 512; thread handles idx = tid, tid+256.
    const bf16* pf[2];
    const bf16* pc[2];
    int sdst[2];
#pragma unroll
    for (int i = 0; i < 2; ++i) {
        int idx = tid + i * 256;
        int row = idx >> 2, kg = idx & 3;
        int gr = r0 + row;
        int t = gr / NU, u = gr - t * NU;
        pf[i] = fproj + ((size_t)(b * TT + t)) * HH + kg * 8;
        pc[i] = cemb + ((size_t)(b * NU + u)) * HH + kg * 8;
        sdst[i] = kg * 1040 + row * 8;
    }
    const bf16* wsrc = Wo_s + (size_t)lane * 8;

    f32x4 acc[4][9];
#pragma unroll
    for (int mt = 0; mt < 4; ++mt)
#pragma unroll
        for (int j = 0; j < 9; ++j) acc[mt][j] = (f32x4){0.f, 0.f, 0.f, 0.f};

    const int aBase = g * 1040 + (wm * 64 + c) * 8;
    const int bBase = g * 2304 + (wn * 144 + c) * 8;

    // ---- prologue: stage k32=0 into buffer 0 ----
    {
        for (int ch = w; ch < 18; ch += 4)
            async_copy16(wsrc + ch * 512, &B_s[0][ch * 512 + lane * 8]);
#pragma unroll
        for (int i = 0; i < 2; ++i) {
            bf16x8 fv = *(const bf16x8*)(pf[i]);
            bf16x8 cv = *(const bf16x8*)(pc[i]);
            bf16x8 av;
#pragma unroll
            for (int e = 0; e < 8; ++e)
                av[e] = (bf16)fast_tanh((float)fv[e] + (float)cv[e]);
            *(bf16x8*)&A_s[0][sdst[i]] = av;
        }
        __syncthreads();
    }

    // ---- main loop: one barrier per k32 ----
    for (int i = 0; i < 16; ++i) {
        const int cur = i & 1, nxt = cur ^ 1;
        // A-register prefetch for i+1 (global->VGPR, consumed after MFMA phase)
        bf16x8 fv2[2], cv2[2];
        if (i < 15) {
            const int kt = (i + 1) * 32;
#pragma unroll
            for (int j = 0; j < 2; ++j) {
                fv2[j] = *(const bf16x8*)(pf[j] + kt);
                cv2[j] = *(const bf16x8*)(pc[j] + kt);
            }
        }
        // MFMA phase on buffers [cur]
        bf16x8 af[4];
#pragma unroll
        for (int mt = 0; mt < 4; ++mt)
            af[mt] = *(const bf16x8*)&A_s[cur][aBase + mt * 128];
#pragma unroll
        for (int j = 0; j < 9; ++j) {
            bf16x8 bv = *(const bf16x8*)&B_s[cur][bBase + j * 128];
#pragma unroll
            for (int mt = 0; mt < 4; ++mt)
                acc[mt][j] = __builtin_amdgcn_mfma_f32_16x16x32_bf16(af[mt], bv, acc[mt][j], 0, 0, 0);
        }
        if (i < 15) {
            // B async stage for i+1 into [nxt] (drained at the barrier below)
            const bf16* wk = wsrc + (size_t)(i + 1) * 9216;
            for (int ch = w; ch < 18; ch += 4)
                async_copy16(wk + ch * 512, &B_s[nxt][ch * 512 + lane * 8]);
            // tanh-stage A(i+1) into [nxt]
#pragma unroll
            for (int j = 0; j < 2; ++j) {
                bf16x8 av;
#pragma unroll
                for (int e = 0; e < 8; ++e)
                    av[e] = (bf16)fast_tanh((float)fv2[j][e] + (float)cv2[j][e]);
                *(bf16x8*)&A_s[nxt][sdst[j]] = av;
            }
        }
        __syncthreads();
    }

    // epilogue: per-wave partial lse over owned 144 cols, cross-wave combine in LDS
    float* pmax0 = red;
    float* pmax1 = red + 128;
    float* psum0 = red + 256;
    float* psum1 = red + 384;
    float* pblank = red + 512;
    float* plex = red + 640;

#pragma unroll
    for (int mt = 0; mt < 4; ++mt) {
#pragma unroll
        for (int r = 0; r < 4; ++r) {
            int row_in = wm * 64 + mt * 16 + g * 4 + r;
            int gr = r0 + row_in;
            int t = gr / NU, u = gr - t * NU;
            (void)t;

            float mx = NEG_INF;
#pragma unroll
            for (int j = 0; j < 9; ++j) {
                int col = wn * 144 + j * 16 + c;
                if (col < NV) mx = fmaxf(mx, acc[mt][j][r]);
            }
#pragma unroll
            for (int s = 1; s < 16; s <<= 1) mx = fmaxf(mx, __shfl_xor(mx, s));
            float sum = 0.f;
#pragma unroll
            for (int j = 0; j < 9; ++j) {
                int col = wn * 144 + j * 16 + c;
                if (col < NV) sum += __expf(acc[mt][j][r] - mx);
            }
#pragma unroll
            for (int s = 1; s < 16; s <<= 1) sum += __shfl_xor(sum, s);

            int L = (u < UU) ? labels[b * UU + u] : -1;  // 1..256 or -1
            int lc = L - wn * 144;
            bool own = (lc >= 0) && (lc < 144);
            int src = (lane & 48) | (lc & 15);
            int jl = lc >> 4;
            float lexv = 0.f;
#pragma unroll
            for (int j = 0; j < 9; ++j) {
                float cand = __shfl(acc[mt][j][r], src);
                if (j == jl) lexv = cand;
            }
            float blankv = __shfl(acc[mt][0][r], lane & 48);  // col 0 (valid for wn==0)

            if (c == 0) {
                if (wn == 0) {
                    pmax0[row_in] = mx;
                    psum0[row_in] = sum;
                    pblank[row_in] = blankv;
                } else {
                    pmax1[row_in] = mx;
                    psum1[row_in] = sum;
                }
                if (own) plex[row_in] = lexv;
            }
        }
    }
    __syncthreads();
    if (tid < 128) {
        int gr = r0 + tid;
        int t = gr / NU, u = gr - t * NU;
        float m0 = pmax0[tid], m1 = pmax1[tid];
        float mx = fmaxf(m0, m1);
        float s = psum0[tid] * __expf(m0 - mx) + psum1[tid] * __expf(m1 - mx);
        float lse = mx + __logf(s);
        float2 v;
        v.x = pblank[tid] - lse;
        v.y = (u < UU) ? (plex[tid] - lse) : 0.f;
        *(float2*)&cl_arr[(((size_t)b * TT + t) * NU + u) * 2] = v;
    }
}

// ---- forward DP: one wave per batch, alpha in 2 regs/lane, 8-deep prefetch ----
__global__ void k_dp(const float* __restrict__ cl,
                     const int* __restrict__ num_frames,
                     const int* __restrict__ num_labels,
                     float* __restrict__ out) {
    const int b = blockIdx.x;
    const int lane = threadIdx.x;
    const int nf = num_frames[b];
    const int nl = num_labels[b];
    const float2* P = (const float2*)(cl + (size_t)b * TT * NU * 2);

    float a_lo = (lane == 0) ? 0.f : NEG_INF;
    float a_hi = NEG_INF;
    const bool hi_act = (lane < 33);

    constexpr int D = 8;
    float2 buf_lo[D], buf_hi[D];
#pragma unroll
    for (int d = 0; d < D; ++d) {
        buf_lo[d] = P[d * NU + lane];
        buf_hi[d] = hi_act ? P[d * NU + 64 + lane] : make_float2(NEG_INF, 0.f);
    }

#pragma unroll 8
    for (int t = 0; t < TT; ++t) {
        const int slot = t & (D - 1);
        float2 v_lo = buf_lo[slot];
        float2 v_hi = buf_hi[slot];
        int tp = t + D;
        if (tp < TT) {
            buf_lo[slot] = P[tp * NU + lane];
            if (hi_act) buf_hi[slot] = P[tp * NU + 64 + lane];
        }
        float e_lo = a_lo + v_lo.y;
        float e_hi = a_hi + v_hi.y;
        float em_lo = __shfl_up(e_lo, 1);
        float em_hi = __shfl_up(e_hi, 1);
        float e63 = __shfl(e_lo, 63);
        if (lane == 0) { em_lo = NEG_INF; em_hi = e63; }
        float new_lo = lae(a_lo + v_lo.x, em_lo);
        float new_hi = lae(a_hi + v_hi.x, em_hi);
        bool act = (t < nf);
        a_lo = act ? new_lo : a_lo;
        if (hi_act) a_hi = act ? new_hi : a_hi;
    }
    float res = (nl < 64) ? __shfl(a_lo, nl) : __shfl(a_hi, nl - 64);
    if (lane == 0) out[b] = -res;
}

extern "C" void kernel_launch(void* const* d_in, const int* in_sizes, int n_in,
                              void* d_out, int out_size, void* d_ws, size_t ws_size,
                              hipStream_t stream) {
    const float* frames = (const float*)d_in[0];
    const int* num_frames = (const int*)d_in[1];
    const int* labels = (const int*)d_in[2];
    const int* num_labels = (const int*)d_in[3];
    const float* Wf = (const float*)d_in[4];
    const float* E = (const float*)d_in[5];
    const float* Wo = (const float*)d_in[6];
    float* out = (float*)d_out;

    char* ws = (char*)d_ws;
    size_t off = 0;
    bf16* Wf_t = (bf16*)(ws + off); off += (size_t)HH * FF * 2;               // 512 KiB
    bf16* Wo_s = (bf16*)(ws + off); off += (size_t)16 * 9216 * 2;             // 288 KiB
    bf16* cemb = (bf16*)(ws + off); off += (size_t)BB * NU * HH * 2;          // 388 KiB
    off = (off + 255) & ~(size_t)255;
    bf16* fproj = (bf16*)(ws + off); off += (size_t)BB * TT * HH * 2;         // 2 MiB
    off = (off + 255) & ~(size_t)255;
    float* cl_arr = (float*)(ws + off); off += (size_t)BB * TT * NU * 2 * 4;  // 1.52 MiB

    hipLaunchKernelGGL(k_prep, dim3(681), dim3(256), 0, stream,
                       Wf, Wo, E, labels, Wf_t, Wo_s, cemb);
    hipLaunchKernelGGL(k_fproj, dim3((BB * TT) / 64, HH / 64), dim3(256), 0, stream,
                       frames, Wf_t, fproj);
    hipLaunchKernelGGL(k_joint, dim3((TT * NU) / 128, BB), dim3(256), 0, stream,
                       fproj, cemb, Wo_s, labels, num_frames, cl_arr);
    hipLaunchKernelGGL(k_dp, dim3(BB), dim3(64), 0, stream,
                       cl_arr, num_frames, num_labels, out);
}

// Round 6
// 248.379 us; speedup vs baseline: 1.5997x; 1.1701x over previous
//
#include <hip/hip_runtime.h>
#include <hip/hip_bf16.h>

// RecognitionLattice: RNN-T style lattice loss.
// k_prep (fused weight shuffles + cemb gather) -> k_fproj GEMM (bf16 out)
// -> k_joint: h=tanh(fproj+cemb) @ Wo, dbuf single-barrier K-loop, fused LSE
// -> k_dp: producer/consumer, 2-step semiring compaction, serial wave on LDS.

#define BB 4
#define TT 512
#define UU 96
#define FF 512
#define HH 512
#define VV 256
#define NV (VV + 1)    // 257 vocab incl. blank
#define NU (UU + 1)    // 97 lattice rows per t
#define NP 288         // 18*16 padded N
#define NEG_INF (-1e30f)

typedef __bf16 bf16;
typedef __bf16 bf16x8 __attribute__((ext_vector_type(8)));
typedef float f32x4 __attribute__((ext_vector_type(4)));

// tanh via hw exp2 + hw rcp: avoids the IEEE div expansion (~12 VALU ops).
__device__ __forceinline__ float fast_tanh(float x) {
    float e = __builtin_amdgcn_exp2f(x * 2.8853900817779268f);  // exp(2x)
    float r = __builtin_amdgcn_rcpf(e + 1.0f);
    return __builtin_fmaf(-2.0f, r, 1.0f);
}

__device__ __forceinline__ float lae(float x, float y) {
    float m = fmaxf(x, y);
    float d = fminf(x, y) - m;
    return m + __logf(1.0f + __expf(d));
}

__device__ __forceinline__ float lse3(float x, float y, float z) {
    float m = fmaxf(fmaxf(x, y), z);
    float s = __expf(x - m) + __expf(y - m) + __expf(z - m);
    return m + __logf(s);
}

__device__ __forceinline__ void async_copy16(const void* g, void* l) {
    __builtin_amdgcn_global_load_lds(
        (const __attribute__((address_space(1))) unsigned int*)g,
        (__attribute__((address_space(3))) unsigned int*)l, 16, 0, 0);
}

// ---- fused prep:
// blk [0,512):      Wf_t[n][k] = bf16(Wf[k][n])
// blk [512,584):    Wo_s[k32][kg][n][8] = bf16(Wo[k32*32+kg*8+e][n]) (n<257 else 0)
// blk [584,681):    cemb[b][u][:] = bf16(E[ctx(b,u)][:])
__global__ void k_prep(const float* __restrict__ Wf, const float* __restrict__ Wo,
                       const float* __restrict__ E, const int* __restrict__ labels,
                       bf16* __restrict__ Wf_t, bf16* __restrict__ Wo_s,
                       bf16* __restrict__ cemb) {
    const int blk = blockIdx.x;
    const int tid = threadIdx.x;
    if (blk < 512) {
        int n = blk;
        for (int k = tid; k < FF; k += 256)
            Wf_t[n * FF + k] = (bf16)Wf[k * HH + n];
    } else if (blk < 584) {
        int idx = (blk - 512) * 256 + tid;  // 0..18431
        int n = idx % NP;
        int rest = idx / NP;
        int kg = rest & 3;
        int k32 = rest >> 2;
        bf16x8 v;
#pragma unroll
        for (int e = 0; e < 8; ++e) {
            int k = k32 * 32 + kg * 8 + e;
            v[e] = (n < NV) ? (bf16)Wo[k * NV + n] : (bf16)0.f;
        }
        *(bf16x8*)&Wo_s[(size_t)idx * 8] = v;
    } else {
        int u = blk - 584;  // 0..96
        for (int b = 0; b < BB; ++b) {
            int ctx = (u == 0) ? 0 : labels[b * UU + (u - 1)];
            const float* src = E + (size_t)ctx * HH;
            bf16* dst = cemb + ((size_t)b * NU + u) * HH;
            for (int i = tid; i < HH; i += 256) dst[i] = (bf16)src[i];
        }
    }
}

// ---- fproj = frames @ Wf  (bf16 MFMA, bf16 out) ----
__global__ __launch_bounds__(256, 2) void k_fproj(
    const float* __restrict__ frames, const bf16* __restrict__ Wf_t,
    bf16* __restrict__ fproj) {
    __shared__ bf16 Alds[64 * 40];
    __shared__ bf16 Blds[64 * 40];
    const int tid = threadIdx.x;
    const int r0 = blockIdx.x * 64;
    const int n0 = blockIdx.y * 64;
    const int lane = tid & 63, w = tid >> 6;
    const int c = lane & 15, g = lane >> 4;

    const int srow = tid >> 2, sko = (tid & 3) * 8;
    const float* fptr = frames + (size_t)(r0 + srow) * FF + sko;
    const bf16* wptr = Wf_t + (size_t)(n0 + srow) * FF + sko;

    f32x4 acc[4];
#pragma unroll
    for (int j = 0; j < 4; ++j) acc[j] = (f32x4){0.f, 0.f, 0.f, 0.f};

    for (int kt = 0; kt < FF; kt += 32) {
        float4 f1 = *(const float4*)(fptr + kt);
        float4 f2 = *(const float4*)(fptr + kt + 4);
        bf16x8 av = {(bf16)f1.x, (bf16)f1.y, (bf16)f1.z, (bf16)f1.w,
                     (bf16)f2.x, (bf16)f2.y, (bf16)f2.z, (bf16)f2.w};
        *(bf16x8*)&Alds[srow * 40 + sko] = av;
        *(bf16x8*)&Blds[srow * 40 + sko] = *(const bf16x8*)(wptr + kt);
        __syncthreads();
        const int m = w * 16;
        bf16x8 af = *(const bf16x8*)&Alds[(m + c) * 40 + g * 8];
#pragma unroll
        for (int j = 0; j < 4; ++j) {
            bf16x8 bv = *(const bf16x8*)&Blds[(j * 16 + c) * 40 + g * 8];
            acc[j] = __builtin_amdgcn_mfma_f32_16x16x32_bf16(af, bv, acc[j], 0, 0, 0);
        }
        __syncthreads();
    }
    const int m = w * 16;
#pragma unroll
    for (int j = 0; j < 4; ++j)
#pragma unroll
        for (int r = 0; r < 4; ++r)
            fproj[(size_t)(r0 + m + g * 4 + r) * HH + n0 + j * 16 + c] = (bf16)acc[j][r];
}

// ---- joint: logits = tanh(fproj[t]+cemb[u]) @ Wo, fused log_softmax extract ----
// grid (388, B), block 256 = 2x2 waves, wave tile 64x144.
// Double-buffered A (tanh-staged) and B (global_load_lds), ONE barrier/iter.
__global__ __launch_bounds__(256, 2) void k_joint(
    const bf16* __restrict__ fproj, const bf16* __restrict__ cemb,
    const bf16* __restrict__ Wo_s, const int* __restrict__ labels,
    const int* __restrict__ num_frames, float* __restrict__ cl_arr) {
    __shared__ bf16 A_s[2][4 * 1040];   // 2 x 8320 B, kg-plane stride 1040 (bank rot)
    __shared__ bf16 B_s[2][18 * 512];   // 2 x 18432 B, flat [kg][n][8]
    __shared__ float red[6 * 128];      // cross-wave LSE combine

    const int tid = threadIdx.x;
    const int b = blockIdx.y;
    const int r0 = blockIdx.x * 128;
    const int nf = num_frames[b];
    if (r0 / NU >= nf) return;  // whole tile beyond active frames: outputs unused

    const int lane = tid & 63, w = tid >> 6;
    const int wm = w & 1, wn = w >> 1;
    const int c = lane & 15, g = lane >> 4;

    // A-staging tasks: 128 rows x 4 kg = 512; thread handles idx = tid, tid+256.
    const bf16* pf[2];
    const bf16* pc[2];
    int sdst[2];
#pragma unroll
    for (int i = 0; i < 2; ++i) {
        int idx = tid + i * 256;
        int row = idx >> 2, kg = idx & 3;
        int gr = r0 + row;
        int t = gr / NU, u = gr - t * NU;
        pf[i] = fproj + ((size_t)(b * TT + t)) * HH + kg * 8;
        pc[i] = cemb + ((size_t)(b * NU + u)) * HH + kg * 8;
        sdst[i] = kg * 1040 + row * 8;
    }
    const bf16* wsrc = Wo_s + (size_t)lane * 8;

    f32x4 acc[4][9];
#pragma unroll
    for (int mt = 0; mt < 4; ++mt)
#pragma unroll
        for (int j = 0; j < 9; ++j) acc[mt][j] = (f32x4){0.f, 0.f, 0.f, 0.f};

    const int aBase = g * 1040 + (wm * 64 + c) * 8;
    const int bBase = g * 2304 + (wn * 144 + c) * 8;

    // ---- prologue: stage k32=0 into buffer 0 ----
    {
        for (int ch = w; ch < 18; ch += 4)
            async_copy16(wsrc + ch * 512, &B_s[0][ch * 512 + lane * 8]);
#pragma unroll
        for (int i = 0; i < 2; ++i) {
            bf16x8 fv = *(const bf16x8*)(pf[i]);
            bf16x8 cv = *(const bf16x8*)(pc[i]);
            bf16x8 av;
#pragma unroll
            for (int e = 0; e < 8; ++e)
                av[e] = (bf16)fast_tanh((float)fv[e] + (float)cv[e]);
            *(bf16x8*)&A_s[0][sdst[i]] = av;
        }
        __syncthreads();
    }

    // ---- main loop: one barrier per k32 ----
    for (int i = 0; i < 16; ++i) {
        const int cur = i & 1, nxt = cur ^ 1;
        bf16x8 fv2[2], cv2[2];
        if (i < 15) {
            const int kt = (i + 1) * 32;
#pragma unroll
            for (int j = 0; j < 2; ++j) {
                fv2[j] = *(const bf16x8*)(pf[j] + kt);
                cv2[j] = *(const bf16x8*)(pc[j] + kt);
            }
        }
        bf16x8 af[4];
#pragma unroll
        for (int mt = 0; mt < 4; ++mt)
            af[mt] = *(const bf16x8*)&A_s[cur][aBase + mt * 128];
#pragma unroll
        for (int j = 0; j < 9; ++j) {
            bf16x8 bv = *(const bf16x8*)&B_s[cur][bBase + j * 128];
#pragma unroll
            for (int mt = 0; mt < 4; ++mt)
                acc[mt][j] = __builtin_amdgcn_mfma_f32_16x16x32_bf16(af[mt], bv, acc[mt][j], 0, 0, 0);
        }
        if (i < 15) {
            const bf16* wk = wsrc + (size_t)(i + 1) * 9216;
            for (int ch = w; ch < 18; ch += 4)
                async_copy16(wk + ch * 512, &B_s[nxt][ch * 512 + lane * 8]);
#pragma unroll
            for (int j = 0; j < 2; ++j) {
                bf16x8 av;
#pragma unroll
                for (int e = 0; e < 8; ++e)
                    av[e] = (bf16)fast_tanh((float)fv2[j][e] + (float)cv2[j][e]);
                *(bf16x8*)&A_s[nxt][sdst[j]] = av;
            }
        }
        __syncthreads();
    }

    // epilogue: per-wave partial lse over owned 144 cols, cross-wave combine in LDS
    float* pmax0 = red;
    float* pmax1 = red + 128;
    float* psum0 = red + 256;
    float* psum1 = red + 384;
    float* pblank = red + 512;
    float* plex = red + 640;

#pragma unroll
    for (int mt = 0; mt < 4; ++mt) {
#pragma unroll
        for (int r = 0; r < 4; ++r) {
            int row_in = wm * 64 + mt * 16 + g * 4 + r;
            int gr = r0 + row_in;
            int t = gr / NU, u = gr - t * NU;
            (void)t;

            float mx = NEG_INF;
#pragma unroll
            for (int j = 0; j < 9; ++j) {
                int col = wn * 144 + j * 16 + c;
                if (col < NV) mx = fmaxf(mx, acc[mt][j][r]);
            }
#pragma unroll
            for (int s = 1; s < 16; s <<= 1) mx = fmaxf(mx, __shfl_xor(mx, s));
            float sum = 0.f;
#pragma unroll
            for (int j = 0; j < 9; ++j) {
                int col = wn * 144 + j * 16 + c;
                if (col < NV) sum += __expf(acc[mt][j][r] - mx);
            }
#pragma unroll
            for (int s = 1; s < 16; s <<= 1) sum += __shfl_xor(sum, s);

            int L = (u < UU) ? labels[b * UU + u] : -1;  // 1..256 or -1
            int lc = L - wn * 144;
            bool own = (lc >= 0) && (lc < 144);
            int src = (lane & 48) | (lc & 15);
            int jl = lc >> 4;
            float lexv = 0.f;
#pragma unroll
            for (int j = 0; j < 9; ++j) {
                float cand = __shfl(acc[mt][j][r], src);
                if (j == jl) lexv = cand;
            }
            float blankv = __shfl(acc[mt][0][r], lane & 48);  // col 0 (valid for wn==0)

            if (c == 0) {
                if (wn == 0) {
                    pmax0[row_in] = mx;
                    psum0[row_in] = sum;
                    pblank[row_in] = blankv;
                } else {
                    pmax1[row_in] = mx;
                    psum1[row_in] = sum;
                }
                if (own) plex[row_in] = lexv;
            }
        }
    }
    __syncthreads();
    if (tid < 128) {
        int gr = r0 + tid;
        int t = gr / NU, u = gr - t * NU;
        float m0 = pmax0[tid], m1 = pmax1[tid];
        float mx = fmaxf(m0, m1);
        float s = psum0[tid] * __expf(m0 - mx) + psum1[tid] * __expf(m1 - mx);
        float lse = mx + __logf(s);
        float2 v;
        v.x = pblank[tid] - lse;
        v.y = (u < UU) ? (plex[tid] - lse) : 0.f;
        *(float2*)&cl_arr[(((size_t)b * TT + t) * NU + u) * 2] = v;
    }
}

// ---- forward DP, producer/consumer.
// Block 256 = 4 waves per batch. Waves 1-3 compose pairs of t-steps into
// banded ops {D0,D1,D2} in LDS (clamped for t>=nf -> uniform 256 iters);
// wave 0 runs the serial chain: a[u] = lse3(a+D0, a[u-1]+D1[u-1], a[u-2]+D2[u-2]).
#define CHUNK 16                    // double-steps per chunk
#define NCHUNK 16                   // 256 double-steps total
#define SSTRIDE 312                 // 3*104 floats per double-step
__global__ __launch_bounds__(256) void k_dp(
    const float* __restrict__ cl, const int* __restrict__ num_frames,
    const int* __restrict__ num_labels, float* __restrict__ out) {
    __shared__ float Dbuf[2][CHUNK * SSTRIDE];  // 39936 B

    const int b = blockIdx.x;
    const int tid = threadIdx.x;
    const int lane = tid & 63, w = tid >> 6;
    const int nf = num_frames[b];
    const float2* P = (const float2*)(cl + (size_t)b * TT * NU * 2);

    // ---- producer: stage chunk c into Dbuf[c&1] ----
    auto stage = [&](int c, int buf) {
        for (int i = tid - 64; i < CHUNK * NU; i += 192) {
            int s = i / NU, u = i - s * NU;
            int t0 = (c * CHUNK + s) * 2;
            float2 z0 = P[t0 * NU + u];
            float2 z1 = P[(t0 + 1) * NU + u];
            float2 z1n = (u < UU) ? P[(t0 + 1) * NU + u + 1] : make_float2(0.f, NEG_INF);
            bool a0 = t0 < nf, a1 = (t0 + 1) < nf;
            float b0 = a0 ? z0.x : 0.f;
            float l0 = (a0 && u < UU) ? z0.y : NEG_INF;
            float b1 = a1 ? z1.x : 0.f;
            float l1 = (a1 && u < UU) ? z1.y : NEG_INF;
            float b1n = a1 ? z1n.x : 0.f;
            float l1n = (a1 && (u + 1) < UU) ? z1n.y : NEG_INF;
            float* d = &Dbuf[buf][s * SSTRIDE];
            d[u] = b0 + b1;                        // D0
            d[104 + u] = lae(l0 + b1n, b0 + l1);   // D1 (arc u -> u+1 over 2 steps)
            d[208 + u] = l0 + l1n;                 // D2 (arc u -> u+2)
        }
    };

    float a_lo = (lane == 0) ? 0.f : NEG_INF;  // alpha[u=lane]
    float a_hi = NEG_INF;                      // alpha[u=64+lane], lane<33
    const int lo_u = lane;
    const int hi_u = 64 + ((lane < 33) ? lane : 0);  // clamp keeps LDS reads in-bounds

    if (w > 0) stage(0, 0);
    __syncthreads();

    for (int c = 0; c < NCHUNK; ++c) {
        const int cb = c & 1;
        if (w > 0) {
            if (c + 1 < NCHUNK) stage(c + 1, cb ^ 1);
        } else {
#pragma unroll
            for (int s = 0; s < CHUNK; ++s) {
                const float* d = &Dbuf[cb][s * SSTRIDE];
                float d0l = d[lo_u], d1l = d[104 + lo_u], d2l = d[208 + lo_u];
                float d0h = d[hi_u], d1h = d[104 + hi_u], d2h = d[208 + hi_u];

                float e0l = a_lo + d0l;
                float e1l = a_lo + d1l;
                float e2l = a_lo + d2l;
                float e0h = a_hi + d0h;
                float e1h = a_hi + d1h;
                float e2h = a_hi + d2h;

                float em1l = __shfl_up(e1l, 1);
                float em2l = __shfl_up(e2l, 2);
                float e1_63 = __shfl(e1l, 63);
                float e2_62 = __shfl(e2l, 62);
                float e2_63 = __shfl(e2l, 63);
                float em1h = __shfl_up(e1h, 1);
                float em2h = __shfl_up(e2h, 2);
                if (lane == 0) { em1l = NEG_INF; em1h = e1_63; em2h = e2_62; }
                if (lane < 2) em2l = NEG_INF;
                if (lane == 1) em2h = e2_63;

                a_lo = lse3(e0l, em1l, em2l);
                float nh = lse3(e0h, em1h, em2h);
                if (lane < 33) a_hi = nh;
            }
        }
        __syncthreads();
    }

    if (w == 0) {
        const int nl = num_labels[b];
        float res = (nl < 64) ? __shfl(a_lo, nl) : __shfl(a_hi, nl - 64);
        if (lane == 0) out[b] = -res;
    }
}

extern "C" void kernel_launch(void* const* d_in, const int* in_sizes, int n_in,
                              void* d_out, int out_size, void* d_ws, size_t ws_size,
                              hipStream_t stream) {
    const float* frames = (const float*)d_in[0];
    const int* num_frames = (const int*)d_in[1];
    const int* labels = (const int*)d_in[2];
    const int* num_labels = (const int*)d_in[3];
    const float* Wf = (const float*)d_in[4];
    const float* E = (const float*)d_in[5];
    const float* Wo = (const float*)d_in[6];
    float* out = (float*)d_out;

    char* ws = (char*)d_ws;
    size_t off = 0;
    bf16* Wf_t = (bf16*)(ws + off); off += (size_t)HH * FF * 2;               // 512 KiB
    bf16* Wo_s = (bf16*)(ws + off); off += (size_t)16 * 9216 * 2;             // 288 KiB
    bf16* cemb = (bf16*)(ws + off); off += (size_t)BB * NU * HH * 2;          // 388 KiB
    off = (off + 255) & ~(size_t)255;
    bf16* fproj = (bf16*)(ws + off); off += (size_t)BB * TT * HH * 2;         // 2 MiB
    off = (off + 255) & ~(size_t)255;
    float* cl_arr = (float*)(ws + off); off += (size_t)BB * TT * NU * 2 * 4;  // 1.52 MiB

    hipLaunchKernelGGL(k_prep, dim3(681), dim3(256), 0, stream,
                       Wf, Wo, E, labels, Wf_t, Wo_s, cemb);
    hipLaunchKernelGGL(k_fproj, dim3((BB * TT) / 64, HH / 64), dim3(256), 0, stream,
                       frames, Wf_t, fproj);
    hipLaunchKernelGGL(k_joint, dim3((TT * NU) / 128, BB), dim3(256), 0, stream,
                       fproj, cemb, Wo_s, labels, num_frames, cl_arr);
    hipLaunchKernelGGL(k_dp, dim3(BB), dim3(256), 0, stream,
                       cl_arr, num_frames, num_labels, out);
}

// Round 7
// 228.762 us; speedup vs baseline: 1.7369x; 1.0858x over previous
//
#include <hip/hip_runtime.h>
#include <hip/hip_bf16.h>

// RecognitionLattice: RNN-T style lattice loss.
// k_prep (fused weight shuffles + cemb gather) -> k_fproj GEMM (bf16 out)
// -> k_joint: h=tanh(fproj+cemb) @ Wo, 512-thr block, 32x144 wave tile
//    (72 AGPR acc -> 4 waves/SIMD), dbuf single-barrier K-loop, fused LSE
// -> k_dp: producer/consumer, 2-step semiring compaction, serial wave on LDS.

#define BB 4
#define TT 512
#define UU 96
#define FF 512
#define HH 512
#define VV 256
#define NV (VV + 1)    // 257 vocab incl. blank
#define NU (UU + 1)    // 97 lattice rows per t
#define NP 288         // 18*16 padded N
#define NEG_INF (-1e30f)

typedef __bf16 bf16;
typedef __bf16 bf16x8 __attribute__((ext_vector_type(8)));
typedef float f32x4 __attribute__((ext_vector_type(4)));

// tanh via hw exp2 + hw rcp: avoids the IEEE div expansion (~12 VALU ops).
__device__ __forceinline__ float fast_tanh(float x) {
    float e = __builtin_amdgcn_exp2f(x * 2.8853900817779268f);  // exp(2x)
    float r = __builtin_amdgcn_rcpf(e + 1.0f);
    return __builtin_fmaf(-2.0f, r, 1.0f);
}

__device__ __forceinline__ float lae(float x, float y) {
    float m = fmaxf(x, y);
    float d = fminf(x, y) - m;
    return m + __logf(1.0f + __expf(d));
}

__device__ __forceinline__ float lse3(float x, float y, float z) {
    float m = fmaxf(fmaxf(x, y), z);
    float s = __expf(x - m) + __expf(y - m) + __expf(z - m);
    return m + __logf(s);
}

__device__ __forceinline__ void async_copy16(const void* g, void* l) {
    __builtin_amdgcn_global_load_lds(
        (const __attribute__((address_space(1))) unsigned int*)g,
        (__attribute__((address_space(3))) unsigned int*)l, 16, 0, 0);
}

// ---- fused prep:
// blk [0,512):      Wf_t[n][k] = bf16(Wf[k][n])
// blk [512,584):    Wo_s[k32][kg][n][8] = bf16(Wo[k32*32+kg*8+e][n]) (n<257 else 0)
// blk [584,681):    cemb[b][u][:] = bf16(E[ctx(b,u)][:])
__global__ void k_prep(const float* __restrict__ Wf, const float* __restrict__ Wo,
                       const float* __restrict__ E, const int* __restrict__ labels,
                       bf16* __restrict__ Wf_t, bf16* __restrict__ Wo_s,
                       bf16* __restrict__ cemb) {
    const int blk = blockIdx.x;
    const int tid = threadIdx.x;
    if (blk < 512) {
        int n = blk;
        for (int k = tid; k < FF; k += 256)
            Wf_t[n * FF + k] = (bf16)Wf[k * HH + n];
    } else if (blk < 584) {
        int idx = (blk - 512) * 256 + tid;  // 0..18431
        int n = idx % NP;
        int rest = idx / NP;
        int kg = rest & 3;
        int k32 = rest >> 2;
        bf16x8 v;
#pragma unroll
        for (int e = 0; e < 8; ++e) {
            int k = k32 * 32 + kg * 8 + e;
            v[e] = (n < NV) ? (bf16)Wo[k * NV + n] : (bf16)0.f;
        }
        *(bf16x8*)&Wo_s[(size_t)idx * 8] = v;
    } else {
        int u = blk - 584;  // 0..96
        for (int b = 0; b < BB; ++b) {
            int ctx = (u == 0) ? 0 : labels[b * UU + (u - 1)];
            const float* src = E + (size_t)ctx * HH;
            bf16* dst = cemb + ((size_t)b * NU + u) * HH;
            for (int i = tid; i < HH; i += 256) dst[i] = (bf16)src[i];
        }
    }
}

// ---- fproj = frames @ Wf  (bf16 MFMA, bf16 out) ----
__global__ __launch_bounds__(256, 2) void k_fproj(
    const float* __restrict__ frames, const bf16* __restrict__ Wf_t,
    bf16* __restrict__ fproj) {
    __shared__ bf16 Alds[64 * 40];
    __shared__ bf16 Blds[64 * 40];
    const int tid = threadIdx.x;
    const int r0 = blockIdx.x * 64;
    const int n0 = blockIdx.y * 64;
    const int lane = tid & 63, w = tid >> 6;
    const int c = lane & 15, g = lane >> 4;

    const int srow = tid >> 2, sko = (tid & 3) * 8;
    const float* fptr = frames + (size_t)(r0 + srow) * FF + sko;
    const bf16* wptr = Wf_t + (size_t)(n0 + srow) * FF + sko;

    f32x4 acc[4];
#pragma unroll
    for (int j = 0; j < 4; ++j) acc[j] = (f32x4){0.f, 0.f, 0.f, 0.f};

    for (int kt = 0; kt < FF; kt += 32) {
        float4 f1 = *(const float4*)(fptr + kt);
        float4 f2 = *(const float4*)(fptr + kt + 4);
        bf16x8 av = {(bf16)f1.x, (bf16)f1.y, (bf16)f1.z, (bf16)f1.w,
                     (bf16)f2.x, (bf16)f2.y, (bf16)f2.z, (bf16)f2.w};
        *(bf16x8*)&Alds[srow * 40 + sko] = av;
        *(bf16x8*)&Blds[srow * 40 + sko] = *(const bf16x8*)(wptr + kt);
        __syncthreads();
        const int m = w * 16;
        bf16x8 af = *(const bf16x8*)&Alds[(m + c) * 40 + g * 8];
#pragma unroll
        for (int j = 0; j < 4; ++j) {
            bf16x8 bv = *(const bf16x8*)&Blds[(j * 16 + c) * 40 + g * 8];
            acc[j] = __builtin_amdgcn_mfma_f32_16x16x32_bf16(af, bv, acc[j], 0, 0, 0);
        }
        __syncthreads();
    }
    const int m = w * 16;
#pragma unroll
    for (int j = 0; j < 4; ++j)
#pragma unroll
        for (int r = 0; r < 4; ++r)
            fproj[(size_t)(r0 + m + g * 4 + r) * HH + n0 + j * 16 + c] = (bf16)acc[j][r];
}

// ---- joint: logits = tanh(fproj[t]+cemb[u]) @ Wo, fused log_softmax extract ----
// grid (388, B), block 512 = 8 waves (4 M-slots x 2 N-halves), wave tile 32x144.
// acc[2][9] = 72 AGPR -> with launch_bounds(512,4) total regs <= 128 ->
// 4 waves/SIMD (16 waves/CU) for latency hiding. Dbuf A+B, one barrier/iter.
__global__ __launch_bounds__(512, 4) void k_joint(
    const bf16* __restrict__ fproj, const bf16* __restrict__ cemb,
    const bf16* __restrict__ Wo_s, const int* __restrict__ labels,
    const int* __restrict__ num_frames, float* __restrict__ cl_arr) {
    __shared__ bf16 A_s[2][4 * 1040];   // 2 x 8320 B, kg-plane stride 1040 (bank rot)
    __shared__ bf16 B_s[2][18 * 512];   // 2 x 18432 B, flat [kg][n][8]
    __shared__ float red[6 * 128];      // cross-wave LSE combine

    const int tid = threadIdx.x;
    const int b = blockIdx.y;
    const int r0 = blockIdx.x * 128;
    const int nf = num_frames[b];
    if (r0 / NU >= nf) return;  // whole tile beyond active frames: outputs unused

    const int lane = tid & 63, w = tid >> 6;
    const int wm = w & 3, wn = w >> 2;
    const int c = lane & 15, g = lane >> 4;

    // A-staging: 128 rows x 4 kg = 512 tasks, one per thread.
    const int arow = tid >> 2, akg = tid & 3;
    {
        // nothing
    }
    const int gr = r0 + arow;
    const int at = gr / NU, au = gr - at * NU;
    const bf16* pf = fproj + ((size_t)(b * TT + at)) * HH + akg * 8;
    const bf16* pc = cemb + ((size_t)(b * NU + au)) * HH + akg * 8;
    const int sdst = akg * 1040 + arow * 8;
    const bf16* wsrc = Wo_s + (size_t)lane * 8;

    f32x4 acc[2][9];
#pragma unroll
    for (int mt = 0; mt < 2; ++mt)
#pragma unroll
        for (int j = 0; j < 9; ++j) acc[mt][j] = (f32x4){0.f, 0.f, 0.f, 0.f};

    const int aBase = g * 1040 + (wm * 32 + c) * 8;
    const int bBase = g * 2304 + (wn * 144 + c) * 8;

    // ---- prologue: stage k32=0 into buffer 0 ----
    {
        for (int ch = w; ch < 18; ch += 8)
            async_copy16(wsrc + ch * 512, &B_s[0][ch * 512 + lane * 8]);
        bf16x8 fv = *(const bf16x8*)pf;
        bf16x8 cv = *(const bf16x8*)pc;
        bf16x8 av;
#pragma unroll
        for (int e = 0; e < 8; ++e)
            av[e] = (bf16)fast_tanh((float)fv[e] + (float)cv[e]);
        *(bf16x8*)&A_s[0][sdst] = av;
        __syncthreads();
    }

    // ---- main loop: one barrier per k32 ----
    for (int i = 0; i < 16; ++i) {
        const int cur = i & 1, nxt = cur ^ 1;
        // A-register prefetch for i+1 (global->VGPR, consumed after MFMA phase)
        bf16x8 fv2, cv2;
        if (i < 15) {
            const int kt = (i + 1) * 32;
            fv2 = *(const bf16x8*)(pf + kt);
            cv2 = *(const bf16x8*)(pc + kt);
        }
        // MFMA phase on buffers [cur]
        bf16x8 af[2];
#pragma unroll
        for (int mt = 0; mt < 2; ++mt)
            af[mt] = *(const bf16x8*)&A_s[cur][aBase + mt * 128];
#pragma unroll
        for (int j = 0; j < 9; ++j) {
            bf16x8 bv = *(const bf16x8*)&B_s[cur][bBase + j * 128];
#pragma unroll
            for (int mt = 0; mt < 2; ++mt)
                acc[mt][j] = __builtin_amdgcn_mfma_f32_16x16x32_bf16(af[mt], bv, acc[mt][j], 0, 0, 0);
        }
        if (i < 15) {
            // B async stage for i+1 into [nxt] (drained at the barrier below)
            const bf16* wk = wsrc + (size_t)(i + 1) * 9216;
            for (int ch = w; ch < 18; ch += 8)
                async_copy16(wk + ch * 512, &B_s[nxt][ch * 512 + lane * 8]);
            // tanh-stage A(i+1) into [nxt]
            bf16x8 av;
#pragma unroll
            for (int e = 0; e < 8; ++e)
                av[e] = (bf16)fast_tanh((float)fv2[e] + (float)cv2[e]);
            *(bf16x8*)&A_s[nxt][sdst] = av;
        }
        __syncthreads();
    }

    // epilogue: per-wave partial lse over owned 144 cols, cross-wave combine in LDS
    float* pmax0 = red;
    float* pmax1 = red + 128;
    float* psum0 = red + 256;
    float* psum1 = red + 384;
    float* pblank = red + 512;
    float* plex = red + 640;

#pragma unroll
    for (int mt = 0; mt < 2; ++mt) {
#pragma unroll
        for (int r = 0; r < 4; ++r) {
            int row_in = wm * 32 + mt * 16 + g * 4 + r;
            int grr = r0 + row_in;
            int u = grr - (grr / NU) * NU;

            float mx = NEG_INF;
#pragma unroll
            for (int j = 0; j < 9; ++j) {
                int col = wn * 144 + j * 16 + c;
                if (col < NV) mx = fmaxf(mx, acc[mt][j][r]);
            }
#pragma unroll
            for (int s = 1; s < 16; s <<= 1) mx = fmaxf(mx, __shfl_xor(mx, s));
            float sum = 0.f;
#pragma unroll
            for (int j = 0; j < 9; ++j) {
                int col = wn * 144 + j * 16 + c;
                if (col < NV) sum += __expf(acc[mt][j][r] - mx);
            }
#pragma unroll
            for (int s = 1; s < 16; s <<= 1) sum += __shfl_xor(sum, s);

            int L = (u < UU) ? labels[b * UU + u] : -1;  // 1..256 or -1
            int lc = L - wn * 144;
            bool own = (lc >= 0) && (lc < 144);
            int src = (lane & 48) | (lc & 15);
            int jl = lc >> 4;
            float lexv = 0.f;
#pragma unroll
            for (int j = 0; j < 9; ++j) {
                float cand = __shfl(acc[mt][j][r], src);
                if (j == jl) lexv = cand;
            }
            float blankv = __shfl(acc[mt][0][r], lane & 48);  // col 0 (valid for wn==0)

            if (c == 0) {
                if (wn == 0) {
                    pmax0[row_in] = mx;
                    psum0[row_in] = sum;
                    pblank[row_in] = blankv;
                } else {
                    pmax1[row_in] = mx;
                    psum1[row_in] = sum;
                }
                if (own) plex[row_in] = lexv;
            }
        }
    }
    __syncthreads();
    if (tid < 128) {
        int grr = r0 + tid;
        int t = grr / NU, u = grr - t * NU;
        float m0 = pmax0[tid], m1 = pmax1[tid];
        float mx = fmaxf(m0, m1);
        float s = psum0[tid] * __expf(m0 - mx) + psum1[tid] * __expf(m1 - mx);
        float lse = mx + __logf(s);
        float2 v;
        v.x = pblank[tid] - lse;
        v.y = (u < UU) ? (plex[tid] - lse) : 0.f;
        *(float2*)&cl_arr[(((size_t)b * TT + t) * NU + u) * 2] = v;
    }
}

// ---- forward DP, producer/consumer.
// Block 256 = 4 waves per batch. Waves 1-3 compose pairs of t-steps into
// banded ops {D0,D1,D2} in LDS (clamped for t>=nf -> uniform 256 iters);
// wave 0 runs the serial chain: a[u] = lse3(a+D0, a[u-1]+D1[u-1], a[u-2]+D2[u-2]).
#define CHUNK 16                    // double-steps per chunk
#define NCHUNK 16                   // 256 double-steps total
#define SSTRIDE 312                 // 3*104 floats per double-step
__global__ __launch_bounds__(256) void k_dp(
    const float* __restrict__ cl, const int* __restrict__ num_frames,
    const int* __restrict__ num_labels, float* __restrict__ out) {
    __shared__ float Dbuf[2][CHUNK * SSTRIDE];  // 39936 B

    const int b = blockIdx.x;
    const int tid = threadIdx.x;
    const int lane = tid & 63, w = tid >> 6;
    const int nf = num_frames[b];
    const float2* P = (const float2*)(cl + (size_t)b * TT * NU * 2);

    // ---- producer: stage chunk c into Dbuf[c&1] ----
    auto stage = [&](int c, int buf) {
        for (int i = tid - 64; i < CHUNK * NU; i += 192) {
            int s = i / NU, u = i - s * NU;
            int t0 = (c * CHUNK + s) * 2;
            float2 z0 = P[t0 * NU + u];
            float2 z1 = P[(t0 + 1) * NU + u];
            float2 z1n = (u < UU) ? P[(t0 + 1) * NU + u + 1] : make_float2(0.f, NEG_INF);
            bool a0 = t0 < nf, a1 = (t0 + 1) < nf;
            float b0 = a0 ? z0.x : 0.f;
            float l0 = (a0 && u < UU) ? z0.y : NEG_INF;
            float b1 = a1 ? z1.x : 0.f;
            float l1 = (a1 && u < UU) ? z1.y : NEG_INF;
            float b1n = a1 ? z1n.x : 0.f;
            float l1n = (a1 && (u + 1) < UU) ? z1n.y : NEG_INF;
            float* d = &Dbuf[buf][s * SSTRIDE];
            d[u] = b0 + b1;                        // D0
            d[104 + u] = lae(l0 + b1n, b0 + l1);   // D1 (arc u -> u+1 over 2 steps)
            d[208 + u] = l0 + l1n;                 // D2 (arc u -> u+2)
        }
    };

    float a_lo = (lane == 0) ? 0.f : NEG_INF;  // alpha[u=lane]
    float a_hi = NEG_INF;                      // alpha[u=64+lane], lane<33
    const int lo_u = lane;
    const int hi_u = 64 + ((lane < 33) ? lane : 0);  // clamp keeps LDS reads in-bounds

    if (w > 0) stage(0, 0);
    __syncthreads();

    for (int c = 0; c < NCHUNK; ++c) {
        const int cb = c & 1;
        if (w > 0) {
            if (c + 1 < NCHUNK) stage(c + 1, cb ^ 1);
        } else {
#pragma unroll
            for (int s = 0; s < CHUNK; ++s) {
                const float* d = &Dbuf[cb][s * SSTRIDE];
                float d0l = d[lo_u], d1l = d[104 + lo_u], d2l = d[208 + lo_u];
                float d0h = d[hi_u], d1h = d[104 + hi_u], d2h = d[208 + hi_u];

                float e0l = a_lo + d0l;
                float e1l = a_lo + d1l;
                float e2l = a_lo + d2l;
                float e0h = a_hi + d0h;
                float e1h = a_hi + d1h;
                float e2h = a_hi + d2h;

                float em1l = __shfl_up(e1l, 1);
                float em2l = __shfl_up(e2l, 2);
                float e1_63 = __shfl(e1l, 63);
                float e2_62 = __shfl(e2l, 62);
                float e2_63 = __shfl(e2l, 63);
                float em1h = __shfl_up(e1h, 1);
                float em2h = __shfl_up(e2h, 2);
                if (lane == 0) { em1l = NEG_INF; em1h = e1_63; em2h = e2_62; }
                if (lane < 2) em2l = NEG_INF;
                if (lane == 1) em2h = e2_63;

                a_lo = lse3(e0l, em1l, em2l);
                float nh = lse3(e0h, em1h, em2h);
                if (lane < 33) a_hi = nh;
            }
        }
        __syncthreads();
    }

    if (w == 0) {
        const int nl = num_labels[b];
        float res = (nl < 64) ? __shfl(a_lo, nl) : __shfl(a_hi, nl - 64);
        if (lane == 0) out[b] = -res;
    }
}

extern "C" void kernel_launch(void* const* d_in, const int* in_sizes, int n_in,
                              void* d_out, int out_size, void* d_ws, size_t ws_size,
                              hipStream_t stream) {
    const float* frames = (const float*)d_in[0];
    const int* num_frames = (const int*)d_in[1];
    const int* labels = (const int*)d_in[2];
    const int* num_labels = (const int*)d_in[3];
    const float* Wf = (const float*)d_in[4];
    const float* E = (const float*)d_in[5];
    const float* Wo = (const float*)d_in[6];
    float* out = (float*)d_out;

    char* ws = (char*)d_ws;
    size_t off = 0;
    bf16* Wf_t = (bf16*)(ws + off); off += (size_t)HH * FF * 2;               // 512 KiB
    bf16* Wo_s = (bf16*)(ws + off); off += (size_t)16 * 9216 * 2;             // 288 KiB
    bf16* cemb = (bf16*)(ws + off); off += (size_t)BB * NU * HH * 2;          // 388 KiB
    off = (off + 255) & ~(size_t)255;
    bf16* fproj = (bf16*)(ws + off); off += (size_t)BB * TT * HH * 2;         // 2 MiB
    off = (off + 255) & ~(size_t)255;
    float* cl_arr = (float*)(ws + off); off += (size_t)BB * TT * NU * 2 * 4;  // 1.52 MiB

    hipLaunchKernelGGL(k_prep, dim3(681), dim3(256), 0, stream,
                       Wf, Wo, E, labels, Wf_t, Wo_s, cemb);
    hipLaunchKernelGGL(k_fproj, dim3((BB * TT) / 64, HH / 64), dim3(256), 0, stream,
                       frames, Wf_t, fproj);
    hipLaunchKernelGGL(k_joint, dim3((TT * NU) / 128, BB), dim3(512), 0, stream,
                       fproj, cemb, Wo_s, labels, num_frames, cl_arr);
    hipLaunchKernelGGL(k_dp, dim3(BB), dim3(256), 0, stream,
                       cl_arr, num_frames, num_labels, out);
}